// Round 1
// baseline (2418.051 us; speedup 1.0000x reference)
//
#include <hip/hip_runtime.h>
#include <cmath>

#define B_SZ 8
#define L_SZ 2048
#define DM 512
#define DI 1024
#define DS 16
#define DC 4
#define DTR 32
#define NE 4
#define NL 2

// ---------------------------------------------------------------------------
// Generic tiled fp32 GEMM: C[b] = A[b] @ W[e_b, layer]  (+ epilogue)
// EPI 0: plain store. EPI 1: softplus(acc + bias). EPI 2: final store with
// expert_id==0 passthrough (writes x instead).
// Tile 64x64, TK=16, 256 threads, 4x4 microtile per thread.
// ---------------------------------------------------------------------------
template<int EPI>
__global__ __launch_bounds__(256) void gemm_kernel(
    const float* __restrict__ Abase, int lda, long aBatch,
    const float* __restrict__ Wbase, long wStride,
    const float* __restrict__ biasBase,
    const float* __restrict__ xpass,
    const int* __restrict__ expert_id, int layer,
    float* __restrict__ Cbase, int ldc, long cBatch,
    int M, int N, int K)
{
  const int b   = blockIdx.z;
  const int eid = expert_id[b];
  const int n0 = blockIdx.x * 64, m0 = blockIdx.y * 64;
  const int tid = threadIdx.x;
  float* Cb = Cbase + (long)b * cBatch;

  if (eid == 0) {
    if (EPI == 2) {
      // passthrough: out = x (bit-exact copy)
      const float* xp = xpass + (long)b * (long)M * N;
      for (int i = tid; i < 64 * 64; i += 256) {
        int r = m0 + (i >> 6), c = n0 + (i & 63);
        Cb[(long)r * ldc + c] = xp[(long)r * N + c];
      }
    }
    return;  // skip all compute for passthrough samples
  }

  const int e = min(max(eid - 1, 0), NE - 1);
  const float* A = Abase + (long)b * aBatch;
  const float* W = Wbase + (long)(e * NL + layer) * wStride;

  __shared__ float As[16][64];  // [k][m]
  __shared__ float Bs[16][64];  // [k][n]

  const int tx = tid & 15, ty = tid >> 4;
  const int arow = tid >> 2, akq = tid & 3;   // A-tile loader: row, k-quad
  const int bk = tid >> 4, bnq = tid & 15;    // B-tile loader: k, n-quad

  float acc[4][4] = {};

  for (int k0 = 0; k0 < K; k0 += 16) {
    float4 av = *(const float4*)&A[(long)(m0 + arow) * lda + k0 + akq * 4];
    float4 wv = *(const float4*)&W[(long)(k0 + bk) * N + n0 + bnq * 4];
    As[akq * 4 + 0][arow] = av.x;
    As[akq * 4 + 1][arow] = av.y;
    As[akq * 4 + 2][arow] = av.z;
    As[akq * 4 + 3][arow] = av.w;
    *(float4*)&Bs[bk][bnq * 4] = wv;
    __syncthreads();
    #pragma unroll
    for (int k = 0; k < 16; ++k) {
      float4 a4 = *(const float4*)&As[k][ty * 4];
      float4 w4 = *(const float4*)&Bs[k][tx * 4];
      float ar[4] = {a4.x, a4.y, a4.z, a4.w};
      float wr[4] = {w4.x, w4.y, w4.z, w4.w};
      #pragma unroll
      for (int i = 0; i < 4; ++i)
        #pragma unroll
        for (int j = 0; j < 4; ++j)
          acc[i][j] = fmaf(ar[i], wr[j], acc[i][j]);
    }
    __syncthreads();
  }

  const float* bias = (EPI == 1) ? (biasBase + (long)(e * NL + layer) * N) : nullptr;
  #pragma unroll
  for (int i = 0; i < 4; ++i) {
    int r = m0 + ty * 4 + i;
    #pragma unroll
    for (int j = 0; j < 4; ++j) {
      int c = n0 + tx * 4 + j;
      float v = acc[i][j];
      if (EPI == 1) {
        v += bias[c];
        v = (v > 20.f) ? v : log1pf(__expf(v));  // softplus
      }
      Cb[(long)r * ldc + c] = v;
    }
  }
}

// ---------------------------------------------------------------------------
// Causal depthwise conv (DC=4) + SiLU: XC[b,t,d] = silu(sum_k xc[t+k-3,d]*w[d,k]+bias)
// xc (pre-conv) lives in XR[:, 0:DI] (ld 2*DI).
// ---------------------------------------------------------------------------
__global__ void conv_silu_kernel(const float* __restrict__ XR,
                                 const float* __restrict__ conv_w,
                                 const float* __restrict__ conv_b,
                                 const int* __restrict__ expert_id, int layer,
                                 float* __restrict__ XC)
{
  const long total = (long)B_SZ * L_SZ * DI;
  for (long idx = (long)blockIdx.x * blockDim.x + threadIdx.x; idx < total;
       idx += (long)gridDim.x * blockDim.x) {
    int d = (int)(idx & (DI - 1));
    long bt = idx >> 10;            // DI = 1024
    int t = (int)(bt & (L_SZ - 1));
    int b = (int)(bt >> 11);        // L = 2048
    int eid = expert_id[b];
    if (eid == 0) continue;
    int e = min(max(eid - 1, 0), NE - 1);
    const float* cw = conv_w + ((long)(e * NL + layer) * DI + d) * DC;
    float acc = conv_b[(long)(e * NL + layer) * DI + d];
    const float* xcol = XR + (long)b * L_SZ * (2 * DI) + d;
    #pragma unroll
    for (int k = 0; k < DC; ++k) {
      int tt = t + k - (DC - 1);
      if (tt >= 0) acc = fmaf(xcol[(long)tt * (2 * DI)], cw[k], acc);
    }
    XC[idx] = acc / (1.f + __expf(-acc));  // silu
  }
}

// ---------------------------------------------------------------------------
// Selective scan. Block = 256 threads = 16 channels x 16 states, one b.
// Grid (DI/16, B). h kept in register per (d,s); shfl-reduce over 16 states.
// Reads: dt = XR[:, 0:DI], res = XR[:, DI:2DI], xc = XC, B/C = PR[:, 32:64].
// Writes y = (h@C + D*xc) * silu(res) into XC in-place.
// ---------------------------------------------------------------------------
#define TCH 64
__global__ __launch_bounds__(256) void scan_kernel(
    const float* __restrict__ XR, const float* __restrict__ XCin,
    const float* __restrict__ PR,
    const float* __restrict__ A_log, const float* __restrict__ Dw,
    const int* __restrict__ expert_id, int layer,
    float* __restrict__ Yout)
{
  const int b = blockIdx.y;
  const int eid = expert_id[b];
  if (eid == 0) return;
  const int e = min(max(eid - 1, 0), NE - 1);
  const int d0 = blockIdx.x * 16;
  const int tid = threadIdx.x;
  const int s = tid & 15, ch = tid >> 4;
  const int d = d0 + ch;

  __shared__ float s_dt[TCH][16], s_xc[TCH][16], s_res[TCH][16];
  __shared__ float s_bc[TCH][32];
  __shared__ float s_y[TCH][16];
  __shared__ float s_D[16];

  if (tid < 16) s_D[tid] = Dw[(long)(e * NL + layer) * DI + d0 + tid];

  const float Aval = -expf(A_log[((long)(e * NL + layer) * DI + d) * DS + s]);
  float h = 0.f;

  const float* dtb = XR + (long)b * L_SZ * (2 * DI);
  const float* xcb = XCin + (long)b * L_SZ * DI;
  const float* prb = PR + (long)b * L_SZ * 64;
  float* yb = Yout + (long)b * L_SZ * DI;

  for (int t0 = 0; t0 < L_SZ; t0 += TCH) {
    for (int i = tid; i < TCH * 16; i += 256) {
      int tr = i >> 4, tc = i & 15;
      long g = (long)(t0 + tr);
      s_dt[tr][tc]  = dtb[g * (2 * DI) + d0 + tc];
      s_res[tr][tc] = dtb[g * (2 * DI) + DI + d0 + tc];
      s_xc[tr][tc]  = xcb[g * DI + d0 + tc];
    }
    for (int i = tid; i < TCH * 32; i += 256) {
      int tr = i >> 5, tc = i & 31;
      s_bc[tr][tc] = prb[(long)(t0 + tr) * 64 + DTR + tc];
    }
    __syncthreads();
    #pragma unroll 4
    for (int t = 0; t < TCH; ++t) {
      float dt  = s_dt[t][ch];
      float xcv = s_xc[t][ch];
      float a = __expf(dt * Aval);
      float bv = s_bc[t][s];
      float cv = s_bc[t][16 + s];
      h = fmaf(a, h, dt * xcv * bv);
      float p = h * cv;
      p += __shfl_xor(p, 1);
      p += __shfl_xor(p, 2);
      p += __shfl_xor(p, 4);
      p += __shfl_xor(p, 8);
      if (s == 0) s_y[t][ch] = p;
    }
    __syncthreads();
    for (int i = tid; i < TCH * 16; i += 256) {
      int tr = i >> 4, tc = i & 15;
      float xcv = s_xc[tr][tc];
      float resv = s_res[tr][tc];
      float y = fmaf(s_D[tc], xcv, s_y[tr][tc]);
      y = y * (resv / (1.f + __expf(-resv)));
      yb[(long)(t0 + tr) * DI + d0 + tc] = y;
    }
    __syncthreads();
  }
}

// ---------------------------------------------------------------------------
extern "C" void kernel_launch(void* const* d_in, const int* in_sizes, int n_in,
                              void* d_out, int out_size, void* d_ws, size_t ws_size,
                              hipStream_t stream)
{
  const float* x      = (const float*)d_in[0];
  const int*   eidp   = (const int*)d_in[1];
  const float* W_in   = (const float*)d_in[2];
  const float* conv_w = (const float*)d_in[3];
  const float* conv_b = (const float*)d_in[4];
  const float* W_x    = (const float*)d_in[5];
  const float* W_dt   = (const float*)d_in[6];
  const float* b_dt   = (const float*)d_in[7];
  const float* A_log  = (const float*)d_in[8];
  const float* Dw     = (const float*)d_in[9];
  const float* W_out  = (const float*)d_in[10];
  float* out = (float*)d_out;
  float* ws  = (float*)d_ws;

  float* XR = ws;                                  // B*L*2048 (xr; later dt|res)
  float* XC = XR + (long)B_SZ * L_SZ * 2 * DI;     // B*L*1024 (xc; later y)
  float* PR = XC + (long)B_SZ * L_SZ * DI;         // B*L*64
  float* XN = PR + (long)B_SZ * L_SZ * 64;         // B*L*512 (layer-0 output)

  for (int l = 0; l < NL; ++l) {
    const float* xin = (l == 0) ? x : XN;

    // 1) xr = xin @ W_in[e,l]  -> XR (xc | res)
    gemm_kernel<0><<<dim3(2 * DI / 64, L_SZ / 64, B_SZ), 256, 0, stream>>>(
        xin, DM, (long)L_SZ * DM,
        W_in, (long)DM * 2 * DI, nullptr, nullptr, eidp, l,
        XR, 2 * DI, (long)L_SZ * 2 * DI, L_SZ, 2 * DI, DM);

    // 2) causal conv + silu -> XC
    conv_silu_kernel<<<4096, 256, 0, stream>>>(XR, conv_w, conv_b, eidp, l, XC);

    // 3) proj = XC @ W_x -> PR (dtproj | B | C)
    gemm_kernel<0><<<dim3(1, L_SZ / 64, B_SZ), 256, 0, stream>>>(
        XC, DI, (long)L_SZ * DI,
        W_x, (long)DI * (DTR + 2 * DS), nullptr, nullptr, eidp, l,
        PR, 64, (long)L_SZ * 64, L_SZ, 64, DI);

    // 4) dt = softplus(PR[:, :32] @ W_dt + b_dt) -> XR[:, 0:DI]
    gemm_kernel<1><<<dim3(DI / 64, L_SZ / 64, B_SZ), 256, 0, stream>>>(
        PR, 64, (long)L_SZ * 64,
        W_dt, (long)DTR * DI, b_dt, nullptr, eidp, l,
        XR, 2 * DI, (long)L_SZ * 2 * DI, L_SZ, DI, DTR);

    // 5) selective scan -> y into XC (in-place)
    scan_kernel<<<dim3(DI / 16, B_SZ), 256, 0, stream>>>(
        XR, XC, PR, A_log, Dw, eidp, l, XC);

    // 6) out = y @ W_out  (final layer fuses the expert_id==0 passthrough)
    if (l == NL - 1) {
      gemm_kernel<2><<<dim3(DM / 64, L_SZ / 64, B_SZ), 256, 0, stream>>>(
          XC, DI, (long)L_SZ * DI,
          W_out, (long)DI * DM, nullptr, x, eidp, l,
          out, DM, (long)L_SZ * DM, L_SZ, DM, DI);
    } else {
      gemm_kernel<0><<<dim3(DM / 64, L_SZ / 64, B_SZ), 256, 0, stream>>>(
          XC, DI, (long)L_SZ * DI,
          W_out, (long)DI * DM, nullptr, nullptr, eidp, l,
          XN, DM, (long)L_SZ * DM, L_SZ, DM, DI);
    }
  }
}

// Round 2
// 1121.424 us; speedup vs baseline: 2.1562x; 2.1562x over previous
//
#include <hip/hip_runtime.h>
#include <hip/hip_bf16.h>
#include <cmath>

#define B_SZ 8
#define L_SZ 2048
#define DM 512
#define DI 1024
#define DS 16
#define DC 4
#define DTR 32
#define NE 4
#define NL 2

typedef __attribute__((ext_vector_type(8))) short bf16x8;
typedef __attribute__((ext_vector_type(8))) unsigned short u16x8;
typedef __attribute__((ext_vector_type(4))) float f32x4;

__device__ __forceinline__ unsigned short f2bf(float x) {
  __hip_bfloat16 h = __float2bfloat16(x);
  return __builtin_bit_cast(unsigned short, h);
}

// 16-lane (DPP-row) sum: quad_perm xor1, quad_perm xor2, row_half_mirror, row_mirror
__device__ __forceinline__ float dpp_sum16(float x) {
  int v;
  v = __builtin_amdgcn_update_dpp(0, __builtin_bit_cast(int, x), 0xB1, 0xF, 0xF, true);
  x += __builtin_bit_cast(float, v);
  v = __builtin_amdgcn_update_dpp(0, __builtin_bit_cast(int, x), 0x4E, 0xF, 0xF, true);
  x += __builtin_bit_cast(float, v);
  v = __builtin_amdgcn_update_dpp(0, __builtin_bit_cast(int, x), 0x141, 0xF, 0xF, true);
  x += __builtin_bit_cast(float, v);
  v = __builtin_amdgcn_update_dpp(0, __builtin_bit_cast(int, x), 0x140, 0xF, 0xF, true);
  x += __builtin_bit_cast(float, v);
  return x;
}

// ---------------------------------------------------------------------------
// Transpose + fp32->bf16: in fp32 [P][R][C] -> out bf16 [P][C][R]
// ---------------------------------------------------------------------------
__global__ __launch_bounds__(256) void transpose_w_kernel(
    const float* __restrict__ in, unsigned short* __restrict__ out, int R, int C)
{
  __shared__ float t[32][33];
  const int p = blockIdx.z;
  const int r0 = blockIdx.y * 32, c0 = blockIdx.x * 32;
  const int tx = threadIdx.x & 31, ty = threadIdx.x >> 5;
  const float* ip = in + (long)p * R * C;
  unsigned short* op = out + (long)p * R * C;
  #pragma unroll
  for (int i = 0; i < 32; i += 8)
    t[ty + i][tx] = ip[(long)(r0 + ty + i) * C + c0 + tx];
  __syncthreads();
  #pragma unroll
  for (int i = 0; i < 32; i += 8)
    op[(long)(c0 + ty + i) * R + r0 + tx] = f2bf(t[tx][ty + i]);
}

// ---------------------------------------------------------------------------
// bf16 MFMA GEMM: C[b] = A[b](fp32,[M][K]) @ W[e,l] with WT bf16 [N][K].
// 128x128 tile, BK=32, 4 waves (2x2), 16 MFMA 16x16x32 per wave per K-iter.
// A reg-staged with fp32->bf16 convert; B reg-staged from pre-converted WT.
// LDS slot-swizzle: 16B slot ^= ((row>>1)&3) on both write and read.
// EPI 0: plain store. EPI 2: final output; expert_id==0 writes xpass through.
// ---------------------------------------------------------------------------
template<int EPI>
__global__ __launch_bounds__(256) void mfma_gemm_kernel(
    const float* __restrict__ Abase, long aBatch, int K,
    const unsigned short* __restrict__ WTbase, long wStride,
    const float* __restrict__ xpass,
    const int* __restrict__ expert_id, int layer,
    float* __restrict__ Cbase, int ldc, long cBatch)
{
  const int b = blockIdx.z;
  const int eid = expert_id[b];
  const int m0 = blockIdx.y * 128, n0 = blockIdx.x * 128;
  const int tid = threadIdx.x;
  float* Cb = Cbase + (long)b * cBatch;

  if (eid == 0) {
    if (EPI == 2) {
      const float* xp = xpass + (long)b * L_SZ * DM;
      for (int i = tid; i < 128 * 128; i += 256) {
        int r = m0 + (i >> 7), c = n0 + (i & 127);
        Cb[(long)r * ldc + c] = xp[(long)r * DM + c];
      }
    }
    return;
  }
  const int e = min(max(eid - 1, 0), NE - 1);
  const float* A = Abase + (long)b * aBatch;
  const unsigned short* WT = WTbase + (long)(e * NL + layer) * wStride;

  __shared__ unsigned short As[128 * 32];
  __shared__ unsigned short Bs[128 * 32];

  // --- staging mapping: thread t covers rows sr and sr+64, k-seg sg (8 elems)
  const int sr = tid >> 2, sg = tid & 3;
  const int slot = sg ^ ((sr >> 1) & 3);  // same for row sr+64 (64>>1 % 4 == 0)
  const float* aP0 = A + (long)(m0 + sr) * K + sg * 8;
  const float* aP1 = A + (long)(m0 + sr + 64) * K + sg * 8;
  const unsigned short* bP0 = WT + (long)(n0 + sr) * K + sg * 8;
  const unsigned short* bP1 = WT + (long)(n0 + sr + 64) * K + sg * 8;
  unsigned short* wA0 = As + sr * 32 + slot * 8;
  unsigned short* wA1 = As + (sr + 64) * 32 + slot * 8;
  unsigned short* wB0 = Bs + sr * 32 + slot * 8;
  unsigned short* wB1 = Bs + (sr + 64) * 32 + slot * 8;

  // --- fragment read offsets (ushort units), swizzled, k0-independent
  const int lane = tid & 63, w = tid >> 6;
  const int wm = w >> 1, wn = w & 1;
  const int lo = lane & 15, hi = lane >> 4;
  int aoff[4], boff[4];
  #pragma unroll
  for (int i = 0; i < 4; ++i) {
    int r = wm * 64 + i * 16 + lo;
    aoff[i] = r * 32 + (hi ^ ((r >> 1) & 3)) * 8;
  }
  #pragma unroll
  for (int j = 0; j < 4; ++j) {
    int r = wn * 64 + j * 16 + lo;
    boff[j] = r * 32 + (hi ^ ((r >> 1) & 3)) * 8;
  }

  f32x4 acc[4][4] = {};

  for (int k0 = 0; k0 < K; k0 += 32) {
    float4 fa0 = *(const float4*)(aP0 + k0);
    float4 fa1 = *(const float4*)(aP0 + k0 + 4);
    float4 fb0 = *(const float4*)(aP1 + k0);
    float4 fb1 = *(const float4*)(aP1 + k0 + 4);
    u16x8 w0 = *(const u16x8*)(bP0 + k0);
    u16x8 w1 = *(const u16x8*)(bP1 + k0);
    u16x8 ha = {f2bf(fa0.x), f2bf(fa0.y), f2bf(fa0.z), f2bf(fa0.w),
                f2bf(fa1.x), f2bf(fa1.y), f2bf(fa1.z), f2bf(fa1.w)};
    u16x8 hb = {f2bf(fb0.x), f2bf(fb0.y), f2bf(fb0.z), f2bf(fb0.w),
                f2bf(fb1.x), f2bf(fb1.y), f2bf(fb1.z), f2bf(fb1.w)};
    *(u16x8*)wA0 = ha;
    *(u16x8*)wA1 = hb;
    *(u16x8*)wB0 = w0;
    *(u16x8*)wB1 = w1;
    __syncthreads();

    bf16x8 af[4], bfr[4];
    #pragma unroll
    for (int i = 0; i < 4; ++i) af[i] = *(const bf16x8*)(As + aoff[i]);
    #pragma unroll
    for (int j = 0; j < 4; ++j) bfr[j] = *(const bf16x8*)(Bs + boff[j]);
    #pragma unroll
    for (int i = 0; i < 4; ++i)
      #pragma unroll
      for (int j = 0; j < 4; ++j)
        acc[i][j] = __builtin_amdgcn_mfma_f32_16x16x32_bf16(af[i], bfr[j], acc[i][j], 0, 0, 0);
    __syncthreads();
  }

  // epilogue: D layout col=lane&15, row=(lane>>4)*4+r
  #pragma unroll
  for (int i = 0; i < 4; ++i) {
    #pragma unroll
    for (int j = 0; j < 4; ++j) {
      #pragma unroll
      for (int r = 0; r < 4; ++r) {
        int row = m0 + wm * 64 + i * 16 + hi * 4 + r;
        int col = n0 + wn * 64 + j * 16 + lo;
        Cb[(long)row * ldc + col] = acc[i][j][r];
      }
    }
  }
}

// ---------------------------------------------------------------------------
// fp32 tiled GEMM for the small dt-path (kept fp32 for accuracy).
// EPI 0: plain. EPI 1: softplus(acc + bias).
// ---------------------------------------------------------------------------
template<int EPI>
__global__ __launch_bounds__(256) void gemm_kernel(
    const float* __restrict__ Abase, int lda, long aBatch,
    const float* __restrict__ Wbase, long wStride,
    const float* __restrict__ biasBase,
    const int* __restrict__ expert_id, int layer,
    float* __restrict__ Cbase, int ldc, long cBatch,
    int M, int N, int K)
{
  const int b   = blockIdx.z;
  const int eid = expert_id[b];
  if (eid == 0) return;
  const int n0 = blockIdx.x * 64, m0 = blockIdx.y * 64;
  const int tid = threadIdx.x;
  float* Cb = Cbase + (long)b * cBatch;

  const int e = min(max(eid - 1, 0), NE - 1);
  const float* A = Abase + (long)b * aBatch;
  const float* W = Wbase + (long)(e * NL + layer) * wStride;

  __shared__ float As[16][64];
  __shared__ float Bs[16][64];

  const int tx = tid & 15, ty = tid >> 4;
  const int arow = tid >> 2, akq = tid & 3;
  const int bk = tid >> 4, bnq = tid & 15;

  float acc[4][4] = {};

  for (int k0 = 0; k0 < K; k0 += 16) {
    float4 av = *(const float4*)&A[(long)(m0 + arow) * lda + k0 + akq * 4];
    float4 wv = *(const float4*)&W[(long)(k0 + bk) * N + n0 + bnq * 4];
    As[akq * 4 + 0][arow] = av.x;
    As[akq * 4 + 1][arow] = av.y;
    As[akq * 4 + 2][arow] = av.z;
    As[akq * 4 + 3][arow] = av.w;
    *(float4*)&Bs[bk][bnq * 4] = wv;
    __syncthreads();
    #pragma unroll
    for (int k = 0; k < 16; ++k) {
      float4 a4 = *(const float4*)&As[k][ty * 4];
      float4 w4 = *(const float4*)&Bs[k][tx * 4];
      float ar[4] = {a4.x, a4.y, a4.z, a4.w};
      float wr[4] = {w4.x, w4.y, w4.z, w4.w};
      #pragma unroll
      for (int i = 0; i < 4; ++i)
        #pragma unroll
        for (int j = 0; j < 4; ++j)
          acc[i][j] = fmaf(ar[i], wr[j], acc[i][j]);
    }
    __syncthreads();
  }

  const float* bias = (EPI == 1) ? (biasBase + (long)(e * NL + layer) * N) : nullptr;
  #pragma unroll
  for (int i = 0; i < 4; ++i) {
    int r = m0 + ty * 4 + i;
    #pragma unroll
    for (int j = 0; j < 4; ++j) {
      int c = n0 + tx * 4 + j;
      float v = acc[i][j];
      if (EPI == 1) {
        v += bias[c];
        v = (v > 20.f) ? v : log1pf(__expf(v));
      }
      Cb[(long)r * ldc + c] = v;
    }
  }
}

// ---------------------------------------------------------------------------
// Causal depthwise conv (DC=4) + SiLU
// ---------------------------------------------------------------------------
__global__ void conv_silu_kernel(const float* __restrict__ XR,
                                 const float* __restrict__ conv_w,
                                 const float* __restrict__ conv_b,
                                 const int* __restrict__ expert_id, int layer,
                                 float* __restrict__ XC)
{
  const long total = (long)B_SZ * L_SZ * DI;
  for (long idx = (long)blockIdx.x * blockDim.x + threadIdx.x; idx < total;
       idx += (long)gridDim.x * blockDim.x) {
    int d = (int)(idx & (DI - 1));
    long bt = idx >> 10;
    int t = (int)(bt & (L_SZ - 1));
    int b = (int)(bt >> 11);
    int eid = expert_id[b];
    if (eid == 0) continue;
    int e = min(max(eid - 1, 0), NE - 1);
    const float* cw = conv_w + ((long)(e * NL + layer) * DI + d) * DC;
    float acc = conv_b[(long)(e * NL + layer) * DI + d];
    const float* xcol = XR + (long)b * L_SZ * (2 * DI) + d;
    #pragma unroll
    for (int k = 0; k < DC; ++k) {
      int tt = t + k - (DC - 1);
      if (tt >= 0) acc = fmaf(xcol[(long)tt * (2 * DI)], cw[k], acc);
    }
    XC[idx] = acc / (1.f + __expf(-acc));
  }
}

// ---------------------------------------------------------------------------
// Selective scan: 16 ch x 16 states per 256-thread block; DPP reduction.
// ---------------------------------------------------------------------------
#define TCH 64
__global__ __launch_bounds__(256) void scan_kernel(
    const float* __restrict__ XR, const float* __restrict__ XCin,
    const float* __restrict__ PR,
    const float* __restrict__ A_log, const float* __restrict__ Dw,
    const int* __restrict__ expert_id, int layer,
    float* __restrict__ Yout)
{
  const int b = blockIdx.y;
  const int eid = expert_id[b];
  if (eid == 0) return;
  const int e = min(max(eid - 1, 0), NE - 1);
  const int d0 = blockIdx.x * 16;
  const int tid = threadIdx.x;
  const int s = tid & 15, ch = tid >> 4;
  const int d = d0 + ch;

  __shared__ float s_dt[TCH][16], s_xc[TCH][16], s_res[TCH][16];
  __shared__ float s_bc[TCH][32];
  __shared__ float s_y[TCH][16];
  __shared__ float s_D[16];

  if (tid < 16) s_D[tid] = Dw[(long)(e * NL + layer) * DI + d0 + tid];

  const float Aval = -expf(A_log[((long)(e * NL + layer) * DI + d) * DS + s]);
  float h = 0.f;

  const float* dtb = XR + (long)b * L_SZ * (2 * DI);
  const float* xcb = XCin + (long)b * L_SZ * DI;
  const float* prb = PR + (long)b * L_SZ * 64;
  float* yb = Yout + (long)b * L_SZ * DI;

  for (int t0 = 0; t0 < L_SZ; t0 += TCH) {
    for (int i = tid; i < TCH * 16; i += 256) {
      int tr = i >> 4, tc = i & 15;
      long g = (long)(t0 + tr);
      s_dt[tr][tc]  = dtb[g * (2 * DI) + d0 + tc];
      s_res[tr][tc] = dtb[g * (2 * DI) + DI + d0 + tc];
      s_xc[tr][tc]  = xcb[g * DI + d0 + tc];
    }
    for (int i = tid; i < TCH * 32; i += 256) {
      int tr = i >> 5, tc = i & 31;
      s_bc[tr][tc] = prb[(long)(t0 + tr) * 64 + DTR + tc];
    }
    __syncthreads();
    #pragma unroll 4
    for (int t = 0; t < TCH; ++t) {
      float dt  = s_dt[t][ch];
      float xcv = s_xc[t][ch];
      float a = __expf(dt * Aval);
      float bv = s_bc[t][s];
      float cv = s_bc[t][16 + s];
      h = fmaf(a, h, dt * xcv * bv);
      float p = dpp_sum16(h * cv);
      if (s == 0) s_y[t][ch] = p;
    }
    __syncthreads();
    for (int i = tid; i < TCH * 16; i += 256) {
      int tr = i >> 4, tc = i & 15;
      float xcv = s_xc[tr][tc];
      float resv = s_res[tr][tc];
      float y = fmaf(s_D[tc], xcv, s_y[tr][tc]);
      y = y * (resv / (1.f + __expf(-resv)));
      yb[(long)(t0 + tr) * DI + d0 + tc] = y;
    }
    __syncthreads();
  }
}

// ---------------------------------------------------------------------------
extern "C" void kernel_launch(void* const* d_in, const int* in_sizes, int n_in,
                              void* d_out, int out_size, void* d_ws, size_t ws_size,
                              hipStream_t stream)
{
  const float* x      = (const float*)d_in[0];
  const int*   eidp   = (const int*)d_in[1];
  const float* W_in   = (const float*)d_in[2];
  const float* conv_w = (const float*)d_in[3];
  const float* conv_b = (const float*)d_in[4];
  const float* W_x    = (const float*)d_in[5];
  const float* W_dt   = (const float*)d_in[6];
  const float* b_dt   = (const float*)d_in[7];
  const float* A_log  = (const float*)d_in[8];
  const float* Dw     = (const float*)d_in[9];
  const float* W_out  = (const float*)d_in[10];
  float* out = (float*)d_out;
  float* ws  = (float*)d_ws;

  float* XR = ws;                       // 33,554,432 f32 (xc_pre|res; later dt|res)
  float* XC = XR + 33554432L;           // 16,777,216 f32 (xc; later y in-place)
  float* PR = XC + 16777216L;           //  1,048,576 f32 (dtproj|B|C)
  float* XN = PR + 1048576L;            //  8,388,608 f32 (layer-0 output)
  unsigned short* WinT  = (unsigned short*)(XN + 8388608L);  // 8.4M bf16 [p][2048][512]
  unsigned short* WoutT = WinT + 8388608L;                   // 4.2M bf16 [p][512][1024]

  // weights -> bf16, transposed to [N][K]
  transpose_w_kernel<<<dim3(2 * DI / 32, DM / 32, NE * NL), 256, 0, stream>>>(
      W_in, WinT, DM, 2 * DI);
  transpose_w_kernel<<<dim3(DM / 32, DI / 32, NE * NL), 256, 0, stream>>>(
      W_out, WoutT, DI, DM);

  for (int l = 0; l < NL; ++l) {
    const float* xin = (l == 0) ? x : XN;

    // 1) xr = xin @ W_in[e,l] -> XR   (bf16 MFMA, M=2048 N=2048 K=512)
    mfma_gemm_kernel<0><<<dim3(2 * DI / 128, L_SZ / 128, B_SZ), 256, 0, stream>>>(
        xin, (long)L_SZ * DM, DM, WinT, (long)(2 * DI) * DM, nullptr, eidp, l,
        XR, 2 * DI, (long)L_SZ * 2 * DI);

    // 2) causal conv + silu -> XC
    conv_silu_kernel<<<4096, 256, 0, stream>>>(XR, conv_w, conv_b, eidp, l, XC);

    // 3) proj = XC @ W_x -> PR  (fp32, N=64)
    gemm_kernel<0><<<dim3(1, L_SZ / 64, B_SZ), 256, 0, stream>>>(
        XC, DI, (long)L_SZ * DI,
        W_x, (long)DI * (DTR + 2 * DS), nullptr, eidp, l,
        PR, 64, (long)L_SZ * 64, L_SZ, 64, DI);

    // 4) dt = softplus(PR[:, :32] @ W_dt + b_dt) -> XR[:, 0:DI]  (fp32)
    gemm_kernel<1><<<dim3(DI / 64, L_SZ / 64, B_SZ), 256, 0, stream>>>(
        PR, 64, (long)L_SZ * 64,
        W_dt, (long)DTR * DI, b_dt, eidp, l,
        XR, 2 * DI, (long)L_SZ * 2 * DI, L_SZ, DI, DTR);

    // 5) selective scan -> y into XC (in-place)
    scan_kernel<<<dim3(DI / 16, B_SZ), 256, 0, stream>>>(
        XR, XC, PR, A_log, Dw, eidp, l, XC);

    // 6) y @ W_out  (bf16 MFMA, M=2048 N=512 K=1024)
    if (l == NL - 1) {
      mfma_gemm_kernel<2><<<dim3(DM / 128, L_SZ / 128, B_SZ), 256, 0, stream>>>(
          XC, (long)L_SZ * DI, DI, WoutT, (long)DM * DI, x, eidp, l,
          out, DM, (long)L_SZ * DM);
    } else {
      mfma_gemm_kernel<0><<<dim3(DM / 128, L_SZ / 128, B_SZ), 256, 0, stream>>>(
          XC, (long)L_SZ * DI, DI, WoutT, (long)DM * DI, nullptr, eidp, l,
          XN, DM, (long)L_SZ * DM);
    }
  }
}

// Round 3
// 748.475 us; speedup vs baseline: 3.2306x; 1.4983x over previous
//
#include <hip/hip_runtime.h>
#include <hip/hip_bf16.h>
#include <cmath>

#define B_SZ 8
#define L_SZ 2048
#define DM 512
#define DI 1024
#define DS 16
#define DC 4
#define DTR 32
#define NE 4
#define NL 2
#define NCH 32
#define TC2 64   // timesteps per chunk = L_SZ / NCH

typedef __attribute__((ext_vector_type(8))) short bf16x8;
typedef __attribute__((ext_vector_type(8))) unsigned short u16x8;
typedef __attribute__((ext_vector_type(4))) float f32x4;

__device__ __forceinline__ unsigned short f2bf(float x) {
  __hip_bfloat16 h = __float2bfloat16(x);
  return __builtin_bit_cast(unsigned short, h);
}

// ---------------------------------------------------------------------------
// Transpose + fp32->bf16: in fp32 [P][R][C] -> out bf16 [P][C][R]
// ---------------------------------------------------------------------------
__global__ __launch_bounds__(256) void transpose_w_kernel(
    const float* __restrict__ in, unsigned short* __restrict__ out, int R, int C)
{
  __shared__ float t[32][33];
  const int p = blockIdx.z;
  const int r0 = blockIdx.y * 32, c0 = blockIdx.x * 32;
  const int tx = threadIdx.x & 31, ty = threadIdx.x >> 5;
  const float* ip = in + (long)p * R * C;
  unsigned short* op = out + (long)p * R * C;
  #pragma unroll
  for (int i = 0; i < 32; i += 8)
    t[ty + i][tx] = ip[(long)(r0 + ty + i) * C + c0 + tx];
  __syncthreads();
  #pragma unroll
  for (int i = 0; i < 32; i += 8)
    op[(long)(c0 + ty + i) * R + r0 + tx] = f2bf(t[tx][ty + i]);
}

// ---------------------------------------------------------------------------
// bf16 MFMA GEMM: C[b] = A[b](fp32,[M][lda>=K]) @ W with WT bf16 [N][K].
// Tile 128 x TN (TN in {128,64}), BK=32, 4 waves.
//   TN=128: waves 2x2, each 64x64 (4x4 frags). TN=64: waves 2x2, each 64x32.
// EPI 0: plain. EPI 1: softplus(acc+bias). EPI 2: final + eid==0 passthrough.
// ---------------------------------------------------------------------------
template<int EPI, int TN>
__global__ __launch_bounds__(256) void mfma_gemm_kernel(
    const float* __restrict__ Abase, long aBatch, int K, int lda,
    const unsigned short* __restrict__ WTbase, long wStride,
    const float* __restrict__ biasBase,
    const float* __restrict__ xpass,
    const int* __restrict__ expert_id, int layer,
    float* __restrict__ Cbase, int ldc, long cBatch)
{
  constexpr int JF = (TN == 128) ? 4 : 2;
  const int b = blockIdx.z;
  const int eid = expert_id[b];
  const int m0 = blockIdx.y * 128, n0 = blockIdx.x * TN;
  const int tid = threadIdx.x;
  float* Cb = Cbase + (long)b * cBatch;

  if (eid == 0) {
    if (EPI == 2) {
      const float* xp = xpass + (long)b * L_SZ * DM;
      for (int i = tid; i < 128 * TN; i += 256) {
        int r = m0 + (i / TN), c = n0 + (i % TN);
        Cb[(long)r * ldc + c] = xp[(long)r * DM + c];
      }
    }
    return;
  }
  const int e = min(max(eid - 1, 0), NE - 1);
  const float* A = Abase + (long)b * aBatch;
  const unsigned short* WT = WTbase + (long)(e * NL + layer) * wStride;

  __shared__ unsigned short As[128 * 32];
  __shared__ unsigned short Bs[TN * 32];

  const int sr = tid >> 2, sg = tid & 3;
  const int slot = sg ^ ((sr >> 1) & 3);
  const float* aP0 = A + (long)(m0 + sr) * lda + sg * 8;
  const float* aP1 = A + (long)(m0 + sr + 64) * lda + sg * 8;
  const unsigned short* bP0 = WT + (long)(n0 + sr) * K + sg * 8;
  const unsigned short* bP1 = WT + (long)(n0 + sr + 64) * K + sg * 8;  // TN==128 only
  unsigned short* wA0 = As + sr * 32 + slot * 8;
  unsigned short* wA1 = As + (sr + 64) * 32 + slot * 8;
  unsigned short* wB0 = Bs + sr * 32 + slot * 8;
  unsigned short* wB1 = Bs + (sr + 64) * 32 + slot * 8;

  const int lane = tid & 63, w = tid >> 6;
  const int wm = w >> 1, wn = w & 1;
  const int lo = lane & 15, hi = lane >> 4;
  int aoff[4], boff[JF];
  #pragma unroll
  for (int i = 0; i < 4; ++i) {
    int r = wm * 64 + i * 16 + lo;
    aoff[i] = r * 32 + (hi ^ ((r >> 1) & 3)) * 8;
  }
  #pragma unroll
  for (int j = 0; j < JF; ++j) {
    int r = wn * (TN / 2) + j * 16 + lo;
    boff[j] = r * 32 + (hi ^ ((r >> 1) & 3)) * 8;
  }

  f32x4 acc[4][JF] = {};

  for (int k0 = 0; k0 < K; k0 += 32) {
    float4 fa0 = *(const float4*)(aP0 + k0);
    float4 fa1 = *(const float4*)(aP0 + k0 + 4);
    float4 fb0 = *(const float4*)(aP1 + k0);
    float4 fb1 = *(const float4*)(aP1 + k0 + 4);
    u16x8 w0 = *(const u16x8*)(bP0 + k0);
    u16x8 ha = {f2bf(fa0.x), f2bf(fa0.y), f2bf(fa0.z), f2bf(fa0.w),
                f2bf(fa1.x), f2bf(fa1.y), f2bf(fa1.z), f2bf(fa1.w)};
    u16x8 hb = {f2bf(fb0.x), f2bf(fb0.y), f2bf(fb0.z), f2bf(fb0.w),
                f2bf(fb1.x), f2bf(fb1.y), f2bf(fb1.z), f2bf(fb1.w)};
    *(u16x8*)wA0 = ha;
    *(u16x8*)wA1 = hb;
    *(u16x8*)wB0 = w0;
    if (TN == 128) {
      u16x8 w1 = *(const u16x8*)(bP1 + k0);
      *(u16x8*)wB1 = w1;
    }
    __syncthreads();

    bf16x8 af[4], bfr[JF];
    #pragma unroll
    for (int i = 0; i < 4; ++i) af[i] = *(const bf16x8*)(As + aoff[i]);
    #pragma unroll
    for (int j = 0; j < JF; ++j) bfr[j] = *(const bf16x8*)(Bs + boff[j]);
    #pragma unroll
    for (int i = 0; i < 4; ++i)
      #pragma unroll
      for (int j = 0; j < JF; ++j)
        acc[i][j] = __builtin_amdgcn_mfma_f32_16x16x32_bf16(af[i], bfr[j], acc[i][j], 0, 0, 0);
    __syncthreads();
  }

  const float* bias = (EPI == 1) ? (biasBase + (long)(e * NL + layer) * DI) : nullptr;
  #pragma unroll
  for (int i = 0; i < 4; ++i) {
    #pragma unroll
    for (int j = 0; j < JF; ++j) {
      #pragma unroll
      for (int r = 0; r < 4; ++r) {
        int row = m0 + wm * 64 + i * 16 + hi * 4 + r;
        int col = n0 + wn * (TN / 2) + j * 16 + lo;
        float v = acc[i][j][r];
        if (EPI == 1) {
          v += bias[col];
          v = (v > 20.f) ? v : log1pf(__expf(v));
        }
        Cb[(long)row * ldc + col] = v;
      }
    }
  }
}

// ---------------------------------------------------------------------------
// Causal depthwise conv (DC=4) + SiLU
// ---------------------------------------------------------------------------
__global__ void conv_silu_kernel(const float* __restrict__ XR,
                                 const float* __restrict__ conv_w,
                                 const float* __restrict__ conv_b,
                                 const int* __restrict__ expert_id, int layer,
                                 float* __restrict__ XC)
{
  const long total = (long)B_SZ * L_SZ * DI;
  for (long idx = (long)blockIdx.x * blockDim.x + threadIdx.x; idx < total;
       idx += (long)gridDim.x * blockDim.x) {
    int d = (int)(idx & (DI - 1));
    long bt = idx >> 10;
    int t = (int)(bt & (L_SZ - 1));
    int b = (int)(bt >> 11);
    int eid = expert_id[b];
    if (eid == 0) continue;
    int e = min(max(eid - 1, 0), NE - 1);
    const float* cw = conv_w + ((long)(e * NL + layer) * DI + d) * DC;
    float acc = conv_b[(long)(e * NL + layer) * DI + d];
    const float* xcol = XR + (long)b * L_SZ * (2 * DI) + d;
    #pragma unroll
    for (int k = 0; k < DC; ++k) {
      int tt = t + k - (DC - 1);
      if (tt >= 0) acc = fmaf(xcol[(long)tt * (2 * DI)], cw[k], acc);
    }
    XC[idx] = acc / (1.f + __expf(-acc));
  }
}

// ---------------------------------------------------------------------------
// Chunked scan, pass 1: per-chunk local scan from h=0; store h_end and S=sum(dt).
// Thread = one channel d of one (b, chunk). All 16 states in registers.
// ---------------------------------------------------------------------------
__global__ __launch_bounds__(256) void scan_p1(
    const float* __restrict__ XR, const float* __restrict__ XC,
    const float* __restrict__ PR, const float* __restrict__ A_log,
    const int* __restrict__ expert_id, int layer,
    float* __restrict__ Hws, float* __restrict__ Sws)
{
  const int b = blockIdx.z, c = blockIdx.y;
  const int eid = expert_id[b];
  if (eid == 0) return;
  const int e = min(max(eid - 1, 0), NE - 1);
  const int d = blockIdx.x * 256 + threadIdx.x;
  const int t0 = c * TC2;

  __shared__ float sB[TC2][16];
  const float* prb = PR + (long)b * L_SZ * 64;
  for (int i = threadIdx.x; i < TC2 * 16; i += 256) {
    int t = i >> 4, s = i & 15;
    sB[t][s] = prb[(long)(t0 + t) * 64 + DTR + s];
  }

  float Aval[16];
  const float* al = A_log + ((long)(e * NL + layer) * DI + d) * DS;
  #pragma unroll
  for (int s = 0; s < 16; ++s) Aval[s] = -expf(al[s]);

  float h[16];
  #pragma unroll
  for (int s = 0; s < 16; ++s) h[s] = 0.f;
  float S = 0.f;

  const float* dtb = XR + (long)b * L_SZ * (2 * DI);
  const float* xcb = XC + (long)b * L_SZ * DI;
  __syncthreads();

  for (int t = 0; t < TC2; ++t) {
    float dt = dtb[(long)(t0 + t) * (2 * DI) + d];
    float xc = xcb[(long)(t0 + t) * DI + d];
    S += dt;
    float dx = dt * xc;
    float4 b0 = *(const float4*)&sB[t][0];
    float4 b1 = *(const float4*)&sB[t][4];
    float4 b2 = *(const float4*)&sB[t][8];
    float4 b3 = *(const float4*)&sB[t][12];
    float bv[16] = {b0.x, b0.y, b0.z, b0.w, b1.x, b1.y, b1.z, b1.w,
                    b2.x, b2.y, b2.z, b2.w, b3.x, b3.y, b3.z, b3.w};
    #pragma unroll
    for (int s = 0; s < 16; ++s)
      h[s] = fmaf(__expf(dt * Aval[s]), h[s], dx * bv[s]);
  }

  const long hoff = (((long)b * NCH + c) * DI + d) * 16;
  #pragma unroll
  for (int s = 0; s < 16; s += 4)
    *(float4*)&Hws[hoff + s] = make_float4(h[s], h[s + 1], h[s + 2], h[s + 3]);
  Sws[((long)b * NCH + c) * DI + d] = S;
}

// ---------------------------------------------------------------------------
// Chunk combine (in-place): H[c] := h_in(c); h_in(c+1) = q_c + exp(A*S_c)*h_in(c)
// Thread per (b,d,s).
// ---------------------------------------------------------------------------
__global__ __launch_bounds__(256) void scan_combine(
    float* __restrict__ Hws, const float* __restrict__ Sws,
    const float* __restrict__ A_log,
    const int* __restrict__ expert_id, int layer)
{
  const int gid = blockIdx.x * 256 + threadIdx.x;
  const int s = gid & 15;
  const int d = (gid >> 4) & (DI - 1);
  const int b = gid >> 14;
  const int eid = expert_id[b];
  if (eid == 0) return;
  const int e = min(max(eid - 1, 0), NE - 1);
  const float Aval = -expf(A_log[((long)(e * NL + layer) * DI + d) * DS + s]);
  float h = 0.f;
  for (int c = 0; c < NCH; ++c) {
    const long off = (((long)b * NCH + c) * DI + d) * 16 + s;
    float q = Hws[off];
    float Sc = Sws[((long)b * NCH + c) * DI + d];
    Hws[off] = h;
    h = fmaf(__expf(Aval * Sc), h, q);
  }
}

// ---------------------------------------------------------------------------
// Chunked scan, pass 2: redo local scan seeded with h_in; emit
// y = (h@C + D*xc) * silu(res), written to XC in-place.
// ---------------------------------------------------------------------------
__global__ __launch_bounds__(256) void scan_p2(
    const float* __restrict__ XR, float* __restrict__ XC,
    const float* __restrict__ PR, const float* __restrict__ A_log,
    const float* __restrict__ Dw, const float* __restrict__ Hws,
    const int* __restrict__ expert_id, int layer)
{
  const int b = blockIdx.z, c = blockIdx.y;
  const int eid = expert_id[b];
  if (eid == 0) return;
  const int e = min(max(eid - 1, 0), NE - 1);
  const int d = blockIdx.x * 256 + threadIdx.x;
  const int t0 = c * TC2;

  __shared__ float sBC[TC2][32];
  const float* prb = PR + (long)b * L_SZ * 64;
  for (int i = threadIdx.x; i < TC2 * 32; i += 256) {
    int t = i >> 5, j = i & 31;
    sBC[t][j] = prb[(long)(t0 + t) * 64 + DTR + j];
  }

  float Aval[16];
  const float* al = A_log + ((long)(e * NL + layer) * DI + d) * DS;
  #pragma unroll
  for (int s = 0; s < 16; ++s) Aval[s] = -expf(al[s]);

  float h[16];
  const long hoff = (((long)b * NCH + c) * DI + d) * 16;
  #pragma unroll
  for (int s = 0; s < 16; s += 4) {
    float4 hv = *(const float4*)&Hws[hoff + s];
    h[s] = hv.x; h[s + 1] = hv.y; h[s + 2] = hv.z; h[s + 3] = hv.w;
  }
  const float Dd = Dw[(long)(e * NL + layer) * DI + d];

  const float* dtb = XR + (long)b * L_SZ * (2 * DI);
  float* xcb = XC + (long)b * L_SZ * DI;
  __syncthreads();

  for (int t = 0; t < TC2; ++t) {
    float dt  = dtb[(long)(t0 + t) * (2 * DI) + d];
    float res = dtb[(long)(t0 + t) * (2 * DI) + DI + d];
    float xc  = xcb[(long)(t0 + t) * DI + d];
    float dx = dt * xc;
    float4 b0 = *(const float4*)&sBC[t][0];
    float4 b1 = *(const float4*)&sBC[t][4];
    float4 b2 = *(const float4*)&sBC[t][8];
    float4 b3 = *(const float4*)&sBC[t][12];
    float4 c0 = *(const float4*)&sBC[t][16];
    float4 c1 = *(const float4*)&sBC[t][20];
    float4 c2 = *(const float4*)&sBC[t][24];
    float4 c3 = *(const float4*)&sBC[t][28];
    float bv[16] = {b0.x, b0.y, b0.z, b0.w, b1.x, b1.y, b1.z, b1.w,
                    b2.x, b2.y, b2.z, b2.w, b3.x, b3.y, b3.z, b3.w};
    float cv[16] = {c0.x, c0.y, c0.z, c0.w, c1.x, c1.y, c1.z, c1.w,
                    c2.x, c2.y, c2.z, c2.w, c3.x, c3.y, c3.z, c3.w};
    float y0 = 0.f, y1 = 0.f;
    #pragma unroll
    for (int s = 0; s < 16; s += 2) {
      h[s]     = fmaf(__expf(dt * Aval[s]),     h[s],     dx * bv[s]);
      h[s + 1] = fmaf(__expf(dt * Aval[s + 1]), h[s + 1], dx * bv[s + 1]);
      y0 = fmaf(h[s], cv[s], y0);
      y1 = fmaf(h[s + 1], cv[s + 1], y1);
    }
    float y = y0 + y1;
    y = fmaf(Dd, xc, y);
    float sil = res / (1.f + __expf(-res));
    xcb[(long)(t0 + t) * DI + d] = y * sil;
  }
}

// ---------------------------------------------------------------------------
extern "C" void kernel_launch(void* const* d_in, const int* in_sizes, int n_in,
                              void* d_out, int out_size, void* d_ws, size_t ws_size,
                              hipStream_t stream)
{
  const float* x      = (const float*)d_in[0];
  const int*   eidp   = (const int*)d_in[1];
  const float* W_in   = (const float*)d_in[2];
  const float* conv_w = (const float*)d_in[3];
  const float* conv_b = (const float*)d_in[4];
  const float* W_x    = (const float*)d_in[5];
  const float* W_dt   = (const float*)d_in[6];
  const float* b_dt   = (const float*)d_in[7];
  const float* A_log  = (const float*)d_in[8];
  const float* Dw     = (const float*)d_in[9];
  const float* W_out  = (const float*)d_in[10];
  float* out = (float*)d_out;
  float* ws  = (float*)d_ws;

  float* XR = ws;                       // 33,554,432 f32 (xc_pre|res; later dt|res)
  float* XC = XR + 33554432L;           // 16,777,216 f32 (xc; later y in-place)
  float* PR = XC + 16777216L;           //  1,048,576 f32 (dtproj|B|C)
  float* XN = PR + 1048576L;            //  8,388,608 f32 (layer-0 output)
  // Hws/Sws overlay XN: live only between scan_p1 and scan_p2 of a layer;
  // XN written after (layer 0) / read before (layer 1) that window.
  float* Hws = XN;                      // 4,194,304 f32
  float* Sws = XN + 4194304L;           //   262,144 f32
  unsigned short* WinT  = (unsigned short*)(XN + 8388608L);  // [p][2048][512]
  unsigned short* WoutT = WinT + 8388608L;                   // [p][512][1024]
  unsigned short* WxT   = WoutT + 4194304L;                  // [p][64][1024]
  unsigned short* WdtT  = WxT + 524288L;                     // [p][1024][32]

  transpose_w_kernel<<<dim3(2 * DI / 32, DM / 32, NE * NL), 256, 0, stream>>>(
      W_in, WinT, DM, 2 * DI);
  transpose_w_kernel<<<dim3(DM / 32, DI / 32, NE * NL), 256, 0, stream>>>(
      W_out, WoutT, DI, DM);
  transpose_w_kernel<<<dim3(2, DI / 32, NE * NL), 256, 0, stream>>>(
      W_x, WxT, DI, 64);
  transpose_w_kernel<<<dim3(DI / 32, 1, NE * NL), 256, 0, stream>>>(
      W_dt, WdtT, DTR, DI);

  for (int l = 0; l < NL; ++l) {
    const float* xin = (l == 0) ? x : XN;

    // 1) xr = xin @ W_in[e,l] -> XR  (M=2048 N=2048 K=512)
    mfma_gemm_kernel<0, 128><<<dim3(2 * DI / 128, L_SZ / 128, B_SZ), 256, 0, stream>>>(
        xin, (long)L_SZ * DM, DM, DM, WinT, (long)(2 * DI) * DM,
        nullptr, nullptr, eidp, l, XR, 2 * DI, (long)L_SZ * 2 * DI);

    // 2) causal conv + silu -> XC
    conv_silu_kernel<<<4096, 256, 0, stream>>>(XR, conv_w, conv_b, eidp, l, XC);

    // 3) proj = XC @ W_x -> PR  (M=2048 N=64 K=1024)
    mfma_gemm_kernel<0, 64><<<dim3(1, L_SZ / 128, B_SZ), 256, 0, stream>>>(
        XC, (long)L_SZ * DI, DI, DI, WxT, (long)64 * DI,
        nullptr, nullptr, eidp, l, PR, 64, (long)L_SZ * 64);

    // 4) dt = softplus(PR[:, :32] @ W_dt + b_dt) -> XR[:, 0:DI]  (M=2048 N=1024 K=32)
    mfma_gemm_kernel<1, 128><<<dim3(DI / 128, L_SZ / 128, B_SZ), 256, 0, stream>>>(
        PR, (long)L_SZ * 64, DTR, 64, WdtT, (long)DI * DTR,
        b_dt, nullptr, eidp, l, XR, 2 * DI, (long)L_SZ * 2 * DI);

    // 5) chunked scan -> y into XC (in-place)
    scan_p1<<<dim3(DI / 256, NCH, B_SZ), 256, 0, stream>>>(
        XR, XC, PR, A_log, eidp, l, Hws, Sws);
    scan_combine<<<(B_SZ * DI * DS) / 256, 256, 0, stream>>>(
        Hws, Sws, A_log, eidp, l);
    scan_p2<<<dim3(DI / 256, NCH, B_SZ), 256, 0, stream>>>(
        XR, XC, PR, A_log, Dw, Hws, eidp, l);

    // 6) y @ W_out  (M=2048 N=512 K=1024)
    if (l == NL - 1) {
      mfma_gemm_kernel<2, 128><<<dim3(DM / 128, L_SZ / 128, B_SZ), 256, 0, stream>>>(
          XC, (long)L_SZ * DI, DI, DI, WoutT, (long)DM * DI,
          nullptr, x, eidp, l, out, DM, (long)L_SZ * DM);
    } else {
      mfma_gemm_kernel<0, 128><<<dim3(DM / 128, L_SZ / 128, B_SZ), 256, 0, stream>>>(
          XC, (long)L_SZ * DI, DI, DI, WoutT, (long)DM * DI,
          nullptr, nullptr, eidp, l, XN, DM, (long)L_SZ * DM);
    }
  }
}

// Round 5
// 691.849 us; speedup vs baseline: 3.4951x; 1.0818x over previous
//
#include <hip/hip_runtime.h>
#include <hip/hip_bf16.h>
#include <cmath>

#define B_SZ 8
#define L_SZ 2048
#define DM 512
#define DI 1024
#define DS 16
#define DC 4
#define DTR 32
#define NE 4
#define NL 2
#define NCH 64
#define TC2 32   // timesteps per chunk = L_SZ / NCH

typedef __attribute__((ext_vector_type(8))) short bf16x8;
typedef __attribute__((ext_vector_type(8))) unsigned short u16x8;
typedef __attribute__((ext_vector_type(4))) float f32x4;

__device__ __forceinline__ unsigned short f2bf(float x) {
  __hip_bfloat16 h = __float2bfloat16(x);
  return __builtin_bit_cast(unsigned short, h);
}
__device__ __forceinline__ float bf2f(unsigned short u) {
  return __builtin_bit_cast(float, (unsigned)u << 16);
}

// async global(16B/lane) -> LDS (wave-uniform base + lane*16)
__device__ __forceinline__ void glds16(const unsigned short* g, unsigned short* l) {
  __builtin_amdgcn_global_load_lds(
      (const __attribute__((address_space(1))) unsigned int*)g,
      (__attribute__((address_space(3))) unsigned int*)l, 16, 0, 0);
}

// ---------------------------------------------------------------------------
// Transpose + fp32->bf16: in fp32 [P][R][C] -> out bf16 [P][C][R]
// ---------------------------------------------------------------------------
__global__ __launch_bounds__(256) void transpose_w_kernel(
    const float* __restrict__ in, unsigned short* __restrict__ out, int R, int C)
{
  __shared__ float t[32][33];
  const int p = blockIdx.z;
  const int r0 = blockIdx.y * 32, c0 = blockIdx.x * 32;
  const int tx = threadIdx.x & 31, ty = threadIdx.x >> 5;
  const float* ip = in + (long)p * R * C;
  unsigned short* op = out + (long)p * R * C;
  #pragma unroll
  for (int i = 0; i < 32; i += 8)
    t[ty + i][tx] = ip[(long)(r0 + ty + i) * C + c0 + tx];
  __syncthreads();
  #pragma unroll
  for (int i = 0; i < 32; i += 8)
    op[(long)(c0 + ty + i) * R + r0 + tx] = f2bf(t[tx][ty + i]);
}

// fp32 -> bf16 elementwise (x shadow)
__global__ __launch_bounds__(256) void f2bf_kernel(
    const float* __restrict__ in, unsigned short* __restrict__ out)
{
  long i = ((long)blockIdx.x * 256 + threadIdx.x) * 4;
  float4 v = *(const float4*)(in + i);
  out[i + 0] = f2bf(v.x); out[i + 1] = f2bf(v.y);
  out[i + 2] = f2bf(v.z); out[i + 3] = f2bf(v.w);
}

// ---------------------------------------------------------------------------
// bf16 MFMA GEMM with global_load_lds staging (m97 structure).
// A bf16 [M][lda], WT bf16 [N][K]. Tile 128 x TN (TN in {128,64}), BK=32.
// EPI 0: fp32 store to Cf.
// EPI 2: fp32 store + eid==0 passthrough of x.
// EPI 3: split: col<DI -> bf16 Cbh, else -> bf16 Cbh2 at col-DI (both ld DI).
// EPI 4: bf16 store to Cbh.
// ---------------------------------------------------------------------------
template<int EPI, int TN>
__global__ __launch_bounds__(256) void gemm_bf16(
    const unsigned short* __restrict__ Abase, long aBatch, int K, int lda,
    const unsigned short* __restrict__ WTbase, long wStride,
    const float* __restrict__ xpass,
    const int* __restrict__ expert_id, int layer,
    float* __restrict__ Cf, unsigned short* __restrict__ Cbh,
    unsigned short* __restrict__ Cbh2,
    int ldc, long cBatch)
{
  const int b = blockIdx.z;
  const int eid = expert_id[b];
  const int m0 = blockIdx.y * 128, n0 = blockIdx.x * TN;
  const int tid = threadIdx.x;

  if (eid == 0) {
    if (EPI == 2) {
      float* Co = Cf + (long)b * cBatch;
      const float* xp = xpass + (long)b * L_SZ * DM;
      for (int i = tid; i < 128 * TN; i += 256) {
        int r = m0 + (i / TN), c = n0 + (i % TN);
        Co[(long)r * ldc + c] = xp[(long)r * DM + c];
      }
    }
    return;
  }
  const int e = min(max(eid - 1, 0), NE - 1);
  const unsigned short* A = Abase + (long)b * aBatch;
  const unsigned short* WT = WTbase + (long)(e * NL + layer) * wStride;

  __shared__ unsigned short As[128 * 32];
  __shared__ unsigned short Bs[TN * 32];

  const int w = tid >> 6, lane = tid & 63;
  const int srow = lane >> 2;          // 0..15
  const int sk = (lane & 3) * 8;       // ushort offset in K

  // A: wave w stages rows [w*32, w*32+32) as two 16-row chunks
  const unsigned short* aG0 = A + (long)(m0 + w * 32 + srow) * lda + sk;
  const unsigned short* aG1 = aG0 + 16 * lda;
  unsigned short* aL0 = As + (w * 32) * 32;
  unsigned short* aL1 = As + (w * 32 + 16) * 32;
  // B: TN==128 -> wave w stages rows [w*32, w*32+32); TN==64 -> rows [w*16, w*16+16)
  const unsigned short* bG0;
  const unsigned short* bG1 = nullptr;
  unsigned short* bL0;
  unsigned short* bL1 = nullptr;
  if (TN == 128) {
    bG0 = WT + (long)(n0 + w * 32 + srow) * K + sk;
    bG1 = bG0 + 16 * K;
    bL0 = Bs + (w * 32) * 32;
    bL1 = Bs + (w * 32 + 16) * 32;
  } else {
    bG0 = WT + (long)(n0 + w * 16 + srow) * K + sk;
    bL0 = Bs + (w * 16) * 32;
  }

  constexpr int JF = (TN == 128) ? 4 : 2;
  const int wm = w >> 1, wn = w & 1;
  const int lo = lane & 15, hi = lane >> 4;
  int aoff[4], boff[JF];
  #pragma unroll
  for (int i = 0; i < 4; ++i)
    aoff[i] = (wm * 64 + i * 16 + lo) * 32 + hi * 8;
  #pragma unroll
  for (int j = 0; j < JF; ++j)
    boff[j] = (wn * (TN / 2) + j * 16 + lo) * 32 + hi * 8;

  f32x4 acc[4][JF] = {};

  for (int k0 = 0; k0 < K; k0 += 32) {
    glds16(aG0 + k0, aL0);
    glds16(aG1 + k0, aL1);
    glds16(bG0 + k0, bL0);
    if (TN == 128) glds16(bG1 + k0, bL1);
    __syncthreads();

    bf16x8 af[4], bfr[JF];
    #pragma unroll
    for (int i = 0; i < 4; ++i) af[i] = *(const bf16x8*)(As + aoff[i]);
    #pragma unroll
    for (int j = 0; j < JF; ++j) bfr[j] = *(const bf16x8*)(Bs + boff[j]);
    #pragma unroll
    for (int i = 0; i < 4; ++i)
      #pragma unroll
      for (int j = 0; j < JF; ++j)
        acc[i][j] = __builtin_amdgcn_mfma_f32_16x16x32_bf16(af[i], bfr[j], acc[i][j], 0, 0, 0);
    __syncthreads();
  }

  // epilogue: D layout col=lane&15, row=(lane>>4)*4+r
  #pragma unroll
  for (int i = 0; i < 4; ++i) {
    #pragma unroll
    for (int j = 0; j < JF; ++j) {
      #pragma unroll
      for (int r = 0; r < 4; ++r) {
        int row = m0 + wm * 64 + i * 16 + hi * 4 + r;
        int col = n0 + wn * (TN / 2) + j * 16 + lo;
        float v = acc[i][j][r];
        if (EPI == 0 || EPI == 2) {
          (Cf + (long)b * cBatch)[(long)row * ldc + col] = v;
        } else if (EPI == 4) {
          (Cbh + (long)b * cBatch)[(long)row * ldc + col] = f2bf(v);
        } else {  // EPI 3: split xc | res, both bf16
          if (col < DI)
            (Cbh + (long)b * cBatch)[(long)row * DI + col] = f2bf(v);
          else
            (Cbh2 + (long)b * cBatch)[(long)row * DI + (col - DI)] = f2bf(v);
        }
      }
    }
  }
}

// ---------------------------------------------------------------------------
// dt GEMM (fp32 A, K=32): DT = softplus(PR[:, :32] @ W_dt + b_dt), fp32 out.
// ---------------------------------------------------------------------------
__global__ __launch_bounds__(256) void gemm_dt(
    const float* __restrict__ PRb, const unsigned short* __restrict__ WTbase,
    const float* __restrict__ biasBase,
    const int* __restrict__ expert_id, int layer,
    float* __restrict__ DTout)
{
  const int b = blockIdx.z;
  const int eid = expert_id[b];
  if (eid == 0) return;
  const int e = min(max(eid - 1, 0), NE - 1);
  const int m0 = blockIdx.y * 128, n0 = blockIdx.x * 128;
  const int tid = threadIdx.x;
  const float* A = PRb + (long)b * L_SZ * 64;
  const unsigned short* WT = WTbase + (long)(e * NL + layer) * DI * DTR;

  __shared__ unsigned short As[128 * 32];
  __shared__ unsigned short Bs[128 * 32];

  const int sr = tid >> 2, sg = tid & 3;
  const int slot = sg ^ ((sr >> 1) & 3);

  {
    float4 fa0 = *(const float4*)(A + (long)(m0 + sr) * 64 + sg * 8);
    float4 fa1 = *(const float4*)(A + (long)(m0 + sr) * 64 + sg * 8 + 4);
    float4 fb0 = *(const float4*)(A + (long)(m0 + sr + 64) * 64 + sg * 8);
    float4 fb1 = *(const float4*)(A + (long)(m0 + sr + 64) * 64 + sg * 8 + 4);
    u16x8 w0 = *(const u16x8*)(WT + (long)(n0 + sr) * DTR + sg * 8);
    u16x8 w1 = *(const u16x8*)(WT + (long)(n0 + sr + 64) * DTR + sg * 8);
    u16x8 ha = {f2bf(fa0.x), f2bf(fa0.y), f2bf(fa0.z), f2bf(fa0.w),
                f2bf(fa1.x), f2bf(fa1.y), f2bf(fa1.z), f2bf(fa1.w)};
    u16x8 hb = {f2bf(fb0.x), f2bf(fb0.y), f2bf(fb0.z), f2bf(fb0.w),
                f2bf(fb1.x), f2bf(fb1.y), f2bf(fb1.z), f2bf(fb1.w)};
    *(u16x8*)(As + sr * 32 + slot * 8) = ha;
    *(u16x8*)(As + (sr + 64) * 32 + slot * 8) = hb;
    *(u16x8*)(Bs + sr * 32 + slot * 8) = w0;
    *(u16x8*)(Bs + (sr + 64) * 32 + slot * 8) = w1;
  }
  __syncthreads();

  const int lane = tid & 63, w = tid >> 6;
  const int wm = w >> 1, wn = w & 1;
  const int lo = lane & 15, hi = lane >> 4;
  f32x4 acc[4][4] = {};
  bf16x8 af[4], bfr[4];
  #pragma unroll
  for (int i = 0; i < 4; ++i) {
    int r = wm * 64 + i * 16 + lo;
    af[i] = *(const bf16x8*)(As + r * 32 + (hi ^ ((r >> 1) & 3)) * 8);
  }
  #pragma unroll
  for (int j = 0; j < 4; ++j) {
    int r = wn * 64 + j * 16 + lo;
    bfr[j] = *(const bf16x8*)(Bs + r * 32 + (hi ^ ((r >> 1) & 3)) * 8);
  }
  #pragma unroll
  for (int i = 0; i < 4; ++i)
    #pragma unroll
    for (int j = 0; j < 4; ++j)
      acc[i][j] = __builtin_amdgcn_mfma_f32_16x16x32_bf16(af[i], bfr[j], acc[i][j], 0, 0, 0);

  const float* bias = biasBase + (long)(e * NL + layer) * DI;
  float* Cb = DTout + (long)b * L_SZ * DI;
  #pragma unroll
  for (int i = 0; i < 4; ++i)
    #pragma unroll
    for (int j = 0; j < 4; ++j)
      #pragma unroll
      for (int r = 0; r < 4; ++r) {
        int row = m0 + wm * 64 + i * 16 + hi * 4 + r;
        int col = n0 + wn * 64 + j * 16 + lo;
        float v = acc[i][j][r] + bias[col];
        v = (v > 20.f) ? v : log1pf(__expf(v));
        Cb[(long)row * DI + col] = v;
      }
}

// ---------------------------------------------------------------------------
// Causal depthwise conv (DC=4) + SiLU: reads bf16 XCP, writes bf16 XCbf
// ---------------------------------------------------------------------------
__global__ __launch_bounds__(256) void conv_silu_kernel(
    const unsigned short* __restrict__ XCP,
    const float* __restrict__ conv_w, const float* __restrict__ conv_b,
    const int* __restrict__ expert_id, int layer,
    unsigned short* __restrict__ XCbf)
{
  const int idx = blockIdx.x * 256 + threadIdx.x;   // B*L*(DI/8) = 2,097,152
  const int d8 = idx & 127;
  const int t = (idx >> 7) & (L_SZ - 1);
  const int b = idx >> 18;
  const int eid = expert_id[b];
  if (eid == 0) return;
  const int e = min(max(eid - 1, 0), NE - 1);
  const int d0 = d8 * 8;

  float acc[8];
  const float* cb = conv_b + (long)(e * NL + layer) * DI + d0;
  #pragma unroll
  for (int j = 0; j < 8; ++j) acc[j] = cb[j];

  const float* cw = conv_w + ((long)(e * NL + layer) * DI + d0) * DC;
  #pragma unroll
  for (int k = 0; k < DC; ++k) {
    int tt = t + k - (DC - 1);
    if (tt < 0) continue;
    u16x8 v = *(const u16x8*)(XCP + ((long)b * L_SZ + tt) * DI + d0);
    #pragma unroll
    for (int j = 0; j < 8; ++j)
      acc[j] = fmaf(bf2f(v[j]), cw[j * DC + k], acc[j]);
  }
  unsigned short* xb = XCbf + ((long)b * L_SZ + t) * DI + d0;
  u16x8 ob;
  #pragma unroll
  for (int j = 0; j < 8; ++j) {
    float v = acc[j] / (1.f + __expf(-acc[j]));
    ob[j] = f2bf(v);
  }
  *(u16x8*)xb = ob;
}

// ---------------------------------------------------------------------------
// Chunked scan pass 1: local scan from h=0 -> Hws (h_end), Sws (sum dt).
// One thread per (b, chunk, d); 16 states in registers.
// exp trick: if A[s] == (s+1)*A[0] (geometric), use powers of g=exp(dt*A[0]).
// ---------------------------------------------------------------------------
__global__ __launch_bounds__(256) void scan_p1(
    const float* __restrict__ DTb, const unsigned short* __restrict__ XCbf,
    const float* __restrict__ PR, const float* __restrict__ A_log,
    const int* __restrict__ expert_id, int layer,
    float* __restrict__ Hws, float* __restrict__ Sws)
{
  const int b = blockIdx.z, c = blockIdx.y;
  const int eid = expert_id[b];
  if (eid == 0) return;
  const int e = min(max(eid - 1, 0), NE - 1);
  const int d = blockIdx.x * 256 + threadIdx.x;
  const int t0 = c * TC2;

  __shared__ float sB[TC2][16];
  const float* prb = PR + (long)b * L_SZ * 64;
  for (int i = threadIdx.x; i < TC2 * 16; i += 256) {
    int t = i >> 4, s = i & 15;
    sB[t][s] = prb[(long)(t0 + t) * 64 + DTR + s];
  }

  float Aval[16];
  const float* al = A_log + ((long)(e * NL + layer) * DI + d) * DS;
  #pragma unroll
  for (int s = 0; s < 16; ++s) Aval[s] = -__expf(al[s]);
  bool geo = true;
  #pragma unroll
  for (int s = 1; s < 16; ++s)
    geo = geo && (fabsf(Aval[s] - Aval[0] * (s + 1)) <= 1e-4f * (s + 1));

  float h[16];
  #pragma unroll
  for (int s = 0; s < 16; ++s) h[s] = 0.f;
  float S = 0.f;

  const float* dtp = DTb + ((long)b * L_SZ + t0) * DI + d;
  const unsigned short* xcp = XCbf + ((long)b * L_SZ + t0) * DI + d;
  __syncthreads();

  if (geo) {
    const float A0 = Aval[0];
    for (int t = 0; t < TC2; ++t) {
      float dt = dtp[(long)t * DI];
      float xc = bf2f(xcp[(long)t * DI]);
      S += dt;
      float dx = dt * xc;
      float4 b0 = *(const float4*)&sB[t][0];
      float4 b1 = *(const float4*)&sB[t][4];
      float4 b2 = *(const float4*)&sB[t][8];
      float4 b3 = *(const float4*)&sB[t][12];
      float bv[16] = {b0.x, b0.y, b0.z, b0.w, b1.x, b1.y, b1.z, b1.w,
                      b2.x, b2.y, b2.z, b2.w, b3.x, b3.y, b3.z, b3.w};
      float g = __expf(dt * A0);
      float ee = g;
      #pragma unroll
      for (int s = 0; s < 16; ++s) {
        h[s] = fmaf(ee, h[s], dx * bv[s]);
        ee *= g;
      }
    }
  } else {
    for (int t = 0; t < TC2; ++t) {
      float dt = dtp[(long)t * DI];
      float xc = bf2f(xcp[(long)t * DI]);
      S += dt;
      float dx = dt * xc;
      float4 b0 = *(const float4*)&sB[t][0];
      float4 b1 = *(const float4*)&sB[t][4];
      float4 b2 = *(const float4*)&sB[t][8];
      float4 b3 = *(const float4*)&sB[t][12];
      float bv[16] = {b0.x, b0.y, b0.z, b0.w, b1.x, b1.y, b1.z, b1.w,
                      b2.x, b2.y, b2.z, b2.w, b3.x, b3.y, b3.z, b3.w};
      #pragma unroll
      for (int s = 0; s < 16; ++s)
        h[s] = fmaf(__expf(dt * Aval[s]), h[s], dx * bv[s]);
    }
  }

  const long hoff = (((long)b * NCH + c) * DI + d) * 16;
  #pragma unroll
  for (int s = 0; s < 16; s += 4)
    *(float4*)&Hws[hoff + s] = make_float4(h[s], h[s + 1], h[s + 2], h[s + 3]);
  Sws[((long)b * NCH + c) * DI + d] = S;
}

// ---------------------------------------------------------------------------
// Chunk combine (in-place): Hws[c] := h_in(c)
// ---------------------------------------------------------------------------
__global__ __launch_bounds__(256) void scan_combine(
    float* __restrict__ Hws, const float* __restrict__ Sws,
    const float* __restrict__ A_log,
    const int* __restrict__ expert_id, int layer)
{
  const int gid = blockIdx.x * 256 + threadIdx.x;
  const int s = gid & 15;
  const int d = (gid >> 4) & (DI - 1);
  const int b = gid >> 14;
  const int eid = expert_id[b];
  if (eid == 0) return;
  const int e = min(max(eid - 1, 0), NE - 1);
  const float Aval = -__expf(A_log[((long)(e * NL + layer) * DI + d) * DS + s]);
  float h = 0.f;
  for (int c = 0; c < NCH; ++c) {
    const long off = (((long)b * NCH + c) * DI + d) * 16 + s;
    float q = Hws[off];
    float Sc = Sws[((long)b * NCH + c) * DI + d];
    Hws[off] = h;
    h = fmaf(__expf(Aval * Sc), h, q);
  }
}

// ---------------------------------------------------------------------------
// Chunked scan pass 2: re-scan seeded with h_in; y=(h@C + D*xc)*silu(res) -> bf16
// ---------------------------------------------------------------------------
__global__ __launch_bounds__(256) void scan_p2(
    const float* __restrict__ DTb, const unsigned short* __restrict__ XCbf,
    const unsigned short* __restrict__ RESb, const float* __restrict__ PR,
    const float* __restrict__ A_log, const float* __restrict__ Dw,
    const float* __restrict__ Hws,
    const int* __restrict__ expert_id, int layer,
    unsigned short* __restrict__ Ybf)
{
  const int b = blockIdx.z, c = blockIdx.y;
  const int eid = expert_id[b];
  if (eid == 0) return;
  const int e = min(max(eid - 1, 0), NE - 1);
  const int d = blockIdx.x * 256 + threadIdx.x;
  const int t0 = c * TC2;

  __shared__ float sBC[TC2][32];
  const float* prb = PR + (long)b * L_SZ * 64;
  for (int i = threadIdx.x; i < TC2 * 32; i += 256) {
    int t = i >> 5, j = i & 31;
    sBC[t][j] = prb[(long)(t0 + t) * 64 + DTR + j];
  }

  float Aval[16];
  const float* al = A_log + ((long)(e * NL + layer) * DI + d) * DS;
  #pragma unroll
  for (int s = 0; s < 16; ++s) Aval[s] = -__expf(al[s]);
  bool geo = true;
  #pragma unroll
  for (int s = 1; s < 16; ++s)
    geo = geo && (fabsf(Aval[s] - Aval[0] * (s + 1)) <= 1e-4f * (s + 1));

  float h[16];
  const long hoff = (((long)b * NCH + c) * DI + d) * 16;
  #pragma unroll
  for (int s = 0; s < 16; s += 4) {
    float4 hv = *(const float4*)&Hws[hoff + s];
    h[s] = hv.x; h[s + 1] = hv.y; h[s + 2] = hv.z; h[s + 3] = hv.w;
  }
  const float Dd = Dw[(long)(e * NL + layer) * DI + d];

  const float* dtp = DTb + ((long)b * L_SZ + t0) * DI + d;
  const unsigned short* xcp = XCbf + ((long)b * L_SZ + t0) * DI + d;
  const unsigned short* rsp = RESb + ((long)b * L_SZ + t0) * DI + d;
  unsigned short* yb = Ybf + ((long)b * L_SZ + t0) * DI + d;
  __syncthreads();

  const float A0 = Aval[0];
  for (int t = 0; t < TC2; ++t) {
    float dt  = dtp[(long)t * DI];
    float res = bf2f(rsp[(long)t * DI]);
    float xc  = bf2f(xcp[(long)t * DI]);
    float dx = dt * xc;
    float4 b0 = *(const float4*)&sBC[t][0];
    float4 b1 = *(const float4*)&sBC[t][4];
    float4 b2 = *(const float4*)&sBC[t][8];
    float4 b3 = *(const float4*)&sBC[t][12];
    float4 c0 = *(const float4*)&sBC[t][16];
    float4 c1 = *(const float4*)&sBC[t][20];
    float4 c2 = *(const float4*)&sBC[t][24];
    float4 c3 = *(const float4*)&sBC[t][28];
    float bv[16] = {b0.x, b0.y, b0.z, b0.w, b1.x, b1.y, b1.z, b1.w,
                    b2.x, b2.y, b2.z, b2.w, b3.x, b3.y, b3.z, b3.w};
    float cv[16] = {c0.x, c0.y, c0.z, c0.w, c1.x, c1.y, c1.z, c1.w,
                    c2.x, c2.y, c2.z, c2.w, c3.x, c3.y, c3.z, c3.w};
    float y = 0.f;
    if (geo) {
      float g = __expf(dt * A0);
      float ee = g;
      #pragma unroll
      for (int s = 0; s < 16; ++s) {
        h[s] = fmaf(ee, h[s], dx * bv[s]);
        y = fmaf(h[s], cv[s], y);
        ee *= g;
      }
    } else {
      #pragma unroll
      for (int s = 0; s < 16; ++s) {
        h[s] = fmaf(__expf(dt * Aval[s]), h[s], dx * bv[s]);
        y = fmaf(h[s], cv[s], y);
      }
    }
    y = fmaf(Dd, xc, y);
    float sil = res / (1.f + __expf(-res));
    yb[(long)t * DI] = f2bf(y * sil);
  }
}

// ---------------------------------------------------------------------------
extern "C" void kernel_launch(void* const* d_in, const int* in_sizes, int n_in,
                              void* d_out, int out_size, void* d_ws, size_t ws_size,
                              hipStream_t stream)
{
  const float* x      = (const float*)d_in[0];
  const int*   eidp   = (const int*)d_in[1];
  const float* W_in   = (const float*)d_in[2];
  const float* conv_w = (const float*)d_in[3];
  const float* conv_b = (const float*)d_in[4];
  const float* W_x    = (const float*)d_in[5];
  const float* W_dt   = (const float*)d_in[6];
  const float* b_dt   = (const float*)d_in[7];
  const float* A_log  = (const float*)d_in[8];
  const float* Dw     = (const float*)d_in[9];
  const float* W_out  = (const float*)d_in[10];
  float* out = (float*)d_out;
  float* ws  = (float*)d_ws;

  // workspace layout — total 251,133,952 B (< proven-safe 265.8 MB)
  float* DT  = ws;                          // 16,777,216 f32 (64 MB)
  float* PR  = DT + 16777216L;              //  1,048,576 f32 ( 4 MB)
  float* Hws = PR + 1048576L;               //  8,388,608 f32 (32 MB)
  float* Sws = Hws + 8388608L;              //    524,288 f32 ( 2 MB)
  unsigned short* XCP  = (unsigned short*)(Sws + 524288L);  // 16.8M bf16 (32 MB)
  unsigned short* Ybf  = XCP;                               // overlay (disjoint liveness)
  unsigned short* XCbf = XCP + 16777216L;                   // 32 MB
  unsigned short* RESb = XCbf + 16777216L;                  // 32 MB
  unsigned short* XB   = RESb + 16777216L;                  // 16 MB (x shadow / XN)
  unsigned short* WinT  = XB + 8388608L;                    // 16 MB [p][2048][512]
  unsigned short* WoutT = WinT + 8388608L;                  //  8 MB [p][512][1024]
  unsigned short* WxT   = WoutT + 4194304L;                 //  1 MB [p][64][1024]
  unsigned short* WdtT  = WxT + 524288L;                    // 0.5 MB [p][1024][32]

  transpose_w_kernel<<<dim3(2 * DI / 32, DM / 32, NE * NL), 256, 0, stream>>>(
      W_in, WinT, DM, 2 * DI);
  transpose_w_kernel<<<dim3(DM / 32, DI / 32, NE * NL), 256, 0, stream>>>(
      W_out, WoutT, DI, DM);
  transpose_w_kernel<<<dim3(2, DI / 32, NE * NL), 256, 0, stream>>>(
      W_x, WxT, DI, 64);
  transpose_w_kernel<<<dim3(DI / 32, 1, NE * NL), 256, 0, stream>>>(
      W_dt, WdtT, DTR, DI);
  f2bf_kernel<<<8192, 256, 0, stream>>>(x, XB);   // 8.4M elems / 4 per thread

  for (int l = 0; l < NL; ++l) {
    // 1) xr = xin @ W_in  (M=2048 N=2048 K=512): split -> XCP bf16 | RESb bf16
    gemm_bf16<3, 128><<<dim3(2 * DI / 128, L_SZ / 128, B_SZ), 256, 0, stream>>>(
        XB, (long)L_SZ * DM, DM, DM, WinT, (long)(2 * DI) * DM,
        nullptr, eidp, l, nullptr, XCP, RESb, 0, (long)L_SZ * DI);

    // 2) conv + silu -> XCbf bf16
    conv_silu_kernel<<<8192, 256, 0, stream>>>(XCP, conv_w, conv_b, eidp, l, XCbf);

    // 3) proj = xc @ W_x -> PR fp32  (M=2048 N=64 K=1024)
    gemm_bf16<0, 64><<<dim3(1, L_SZ / 128, B_SZ), 256, 0, stream>>>(
        XCbf, (long)L_SZ * DI, DI, DI, WxT, (long)64 * DI,
        nullptr, eidp, l, PR, nullptr, nullptr, 64, (long)L_SZ * 64);

    // 4) dt = softplus(PR[:,:32] @ W_dt + b_dt) -> DT fp32
    gemm_dt<<<dim3(DI / 128, L_SZ / 128, B_SZ), 256, 0, stream>>>(
        PR, WdtT, b_dt, eidp, l, DT);

    // 5) chunked scan -> Ybf bf16 (overlays XCP, dead after conv)
    scan_p1<<<dim3(DI / 256, NCH, B_SZ), 256, 0, stream>>>(
        DT, XCbf, PR, A_log, eidp, l, Hws, Sws);
    scan_combine<<<(B_SZ * DI * DS) / 256, 256, 0, stream>>>(
        Hws, Sws, A_log, eidp, l);
    scan_p2<<<dim3(DI / 256, NCH, B_SZ), 256, 0, stream>>>(
        DT, XCbf, RESb, PR, A_log, Dw, Hws, eidp, l, Ybf);

    // 6) y @ W_out  (M=2048 N=512 K=1024)
    if (l == NL - 1) {
      gemm_bf16<2, 128><<<dim3(DM / 128, L_SZ / 128, B_SZ), 256, 0, stream>>>(
          Ybf, (long)L_SZ * DI, DI, DI, WoutT, (long)DM * DI,
          x, eidp, l, out, nullptr, nullptr, DM, (long)L_SZ * DM);
    } else {
      gemm_bf16<4, 128><<<dim3(DM / 128, L_SZ / 128, B_SZ), 256, 0, stream>>>(
          Ybf, (long)L_SZ * DI, DI, DI, WoutT, (long)DM * DI,
          nullptr, eidp, l, nullptr, XB, nullptr, DM, (long)L_SZ * DM);
    }
  }
}

// Round 6
// 534.408 us; speedup vs baseline: 4.5247x; 1.2946x over previous
//
#include <hip/hip_runtime.h>
#include <hip/hip_bf16.h>
#include <cmath>

#define B_SZ 8
#define L_SZ 2048
#define DM 512
#define DI 1024
#define DS 16
#define DC 4
#define DTR 32
#define NE 4
#define NL 2
#define NCH 64
#define TC2 32   // timesteps per chunk = L_SZ / NCH
#define TPER 8   // timesteps per conv thread

typedef __attribute__((ext_vector_type(8))) short bf16x8;
typedef __attribute__((ext_vector_type(8))) unsigned short u16x8;
typedef __attribute__((ext_vector_type(4))) float f32x4;

__device__ __forceinline__ unsigned short f2bf(float x) {
  __hip_bfloat16 h = __float2bfloat16(x);
  return __builtin_bit_cast(unsigned short, h);
}
__device__ __forceinline__ float bf2f(unsigned short u) {
  return __builtin_bit_cast(float, (unsigned)u << 16);
}

// async global(16B/lane) -> LDS (wave-uniform base + lane*16)
__device__ __forceinline__ void glds16(const unsigned short* g, unsigned short* l) {
  __builtin_amdgcn_global_load_lds(
      (const __attribute__((address_space(1))) unsigned int*)g,
      (__attribute__((address_space(3))) unsigned int*)l, 16, 0, 0);
}

// ---------------------------------------------------------------------------
// Transpose + fp32->bf16: in fp32 [P][R][C] -> out bf16 [P][C][R]
// ---------------------------------------------------------------------------
__global__ __launch_bounds__(256) void transpose_w_kernel(
    const float* __restrict__ in, unsigned short* __restrict__ out, int R, int C)
{
  __shared__ float t[32][33];
  const int p = blockIdx.z;
  const int r0 = blockIdx.y * 32, c0 = blockIdx.x * 32;
  const int tx = threadIdx.x & 31, ty = threadIdx.x >> 5;
  const float* ip = in + (long)p * R * C;
  unsigned short* op = out + (long)p * R * C;
  #pragma unroll
  for (int i = 0; i < 32; i += 8)
    t[ty + i][tx] = ip[(long)(r0 + ty + i) * C + c0 + tx];
  __syncthreads();
  #pragma unroll
  for (int i = 0; i < 32; i += 8)
    op[(long)(c0 + ty + i) * R + r0 + tx] = f2bf(t[tx][ty + i]);
}

// fp32 -> bf16 elementwise (x shadow)
__global__ __launch_bounds__(256) void f2bf_kernel(
    const float* __restrict__ in, unsigned short* __restrict__ out)
{
  long i = ((long)blockIdx.x * 256 + threadIdx.x) * 4;
  float4 v = *(const float4*)(in + i);
  out[i + 0] = f2bf(v.x); out[i + 1] = f2bf(v.y);
  out[i + 2] = f2bf(v.z); out[i + 3] = f2bf(v.w);
}

// ---------------------------------------------------------------------------
// bf16 MFMA GEMM with global_load_lds staging (m97 structure).
// A bf16 [M][lda], WT bf16 [N][K]. Tile TM x TN (each 64 or 128), BK=32,
// 4 waves (2x2).
// EPI 0: fp32 store to Cf.
// EPI 2: fp32 store + eid==0 passthrough of x.
// EPI 3: split: col<DI -> bf16 Cbh, else -> bf16 Cbh2 at col-DI (both ld DI).
// EPI 4: bf16 store to Cbh.
// ---------------------------------------------------------------------------
template<int EPI, int TM, int TN>
__global__ __launch_bounds__(256) void gemm_bf16(
    const unsigned short* __restrict__ Abase, long aBatch, int K, int lda,
    const unsigned short* __restrict__ WTbase, long wStride,
    const float* __restrict__ xpass,
    const int* __restrict__ expert_id, int layer,
    float* __restrict__ Cf, unsigned short* __restrict__ Cbh,
    unsigned short* __restrict__ Cbh2,
    int ldc, long cBatch)
{
  constexpr int IF = TM / 32;      // M-frags per wave
  constexpr int JF = TN / 32;      // N-frags per wave
  constexpr int AST = TM / 4;      // A rows staged per wave
  constexpr int BST = TN / 4;      // B rows staged per wave

  const int b = blockIdx.z;
  const int eid = expert_id[b];
  const int m0 = blockIdx.y * TM, n0 = blockIdx.x * TN;
  const int tid = threadIdx.x;

  if (eid == 0) {
    if (EPI == 2) {
      float* Co = Cf + (long)b * cBatch;
      const float* xp = xpass + (long)b * L_SZ * DM;
      for (int i = tid; i < TM * TN; i += 256) {
        int r = m0 + (i / TN), c = n0 + (i % TN);
        Co[(long)r * ldc + c] = xp[(long)r * DM + c];
      }
    }
    return;
  }
  const int e = min(max(eid - 1, 0), NE - 1);
  const unsigned short* A = Abase + (long)b * aBatch;
  const unsigned short* WT = WTbase + (long)(e * NL + layer) * wStride;

  __shared__ unsigned short As[TM * 32];
  __shared__ unsigned short Bs[TN * 32];

  const int w = tid >> 6, lane = tid & 63;
  const int srow = lane >> 2;          // 0..15
  const int sk = (lane & 3) * 8;       // ushort offset in K

  // A: wave w stages rows [w*AST, (w+1)*AST) in 16-row chunks
  const unsigned short* aG0 = A + (long)(m0 + w * AST + srow) * lda + sk;
  const unsigned short* aG1 = aG0 + 16 * lda;         // used iff AST==32
  unsigned short* aL0 = As + (w * AST) * 32;
  unsigned short* aL1 = As + (w * AST + 16) * 32;
  const unsigned short* bG0 = WT + (long)(n0 + w * BST + srow) * K + sk;
  const unsigned short* bG1 = bG0 + 16 * K;           // used iff BST==32
  unsigned short* bL0 = Bs + (w * BST) * 32;
  unsigned short* bL1 = Bs + (w * BST + 16) * 32;

  const int wm = w >> 1, wn = w & 1;
  const int lo = lane & 15, hi = lane >> 4;
  int aoff[IF], boff[JF];
  #pragma unroll
  for (int i = 0; i < IF; ++i)
    aoff[i] = (wm * (TM / 2) + i * 16 + lo) * 32 + hi * 8;
  #pragma unroll
  for (int j = 0; j < JF; ++j)
    boff[j] = (wn * (TN / 2) + j * 16 + lo) * 32 + hi * 8;

  f32x4 acc[IF][JF] = {};

  for (int k0 = 0; k0 < K; k0 += 32) {
    glds16(aG0 + k0, aL0);
    if (AST == 32) glds16(aG1 + k0, aL1);
    glds16(bG0 + k0, bL0);
    if (BST == 32) glds16(bG1 + k0, bL1);
    __syncthreads();

    bf16x8 af[IF], bfr[JF];
    #pragma unroll
    for (int i = 0; i < IF; ++i) af[i] = *(const bf16x8*)(As + aoff[i]);
    #pragma unroll
    for (int j = 0; j < JF; ++j) bfr[j] = *(const bf16x8*)(Bs + boff[j]);
    #pragma unroll
    for (int i = 0; i < IF; ++i)
      #pragma unroll
      for (int j = 0; j < JF; ++j)
        acc[i][j] = __builtin_amdgcn_mfma_f32_16x16x32_bf16(af[i], bfr[j], acc[i][j], 0, 0, 0);
    __syncthreads();
  }

  // epilogue: D layout col=lane&15, row=(lane>>4)*4+r
  #pragma unroll
  for (int i = 0; i < IF; ++i) {
    #pragma unroll
    for (int j = 0; j < JF; ++j) {
      #pragma unroll
      for (int r = 0; r < 4; ++r) {
        int row = m0 + wm * (TM / 2) + i * 16 + hi * 4 + r;
        int col = n0 + wn * (TN / 2) + j * 16 + lo;
        float v = acc[i][j][r];
        if (EPI == 0 || EPI == 2) {
          (Cf + (long)b * cBatch)[(long)row * ldc + col] = v;
        } else if (EPI == 4) {
          (Cbh + (long)b * cBatch)[(long)row * ldc + col] = f2bf(v);
        } else {  // EPI 3: split xc | res, both bf16
          if (col < DI)
            (Cbh + (long)b * cBatch)[(long)row * DI + col] = f2bf(v);
          else
            (Cbh2 + (long)b * cBatch)[(long)row * DI + (col - DI)] = f2bf(v);
        }
      }
    }
  }
}

// ---------------------------------------------------------------------------
// dt GEMM (fp32 A, K=32): DT = softplus(PR[:, :32] @ W_dt + b_dt), fp32 out.
// ---------------------------------------------------------------------------
__global__ __launch_bounds__(256) void gemm_dt(
    const float* __restrict__ PRb, const unsigned short* __restrict__ WTbase,
    const float* __restrict__ biasBase,
    const int* __restrict__ expert_id, int layer,
    float* __restrict__ DTout)
{
  const int b = blockIdx.z;
  const int eid = expert_id[b];
  if (eid == 0) return;
  const int e = min(max(eid - 1, 0), NE - 1);
  const int m0 = blockIdx.y * 128, n0 = blockIdx.x * 128;
  const int tid = threadIdx.x;
  const float* A = PRb + (long)b * L_SZ * 64;
  const unsigned short* WT = WTbase + (long)(e * NL + layer) * DI * DTR;

  __shared__ unsigned short As[128 * 32];
  __shared__ unsigned short Bs[128 * 32];

  const int sr = tid >> 2, sg = tid & 3;
  const int slot = sg ^ ((sr >> 1) & 3);

  {
    float4 fa0 = *(const float4*)(A + (long)(m0 + sr) * 64 + sg * 8);
    float4 fa1 = *(const float4*)(A + (long)(m0 + sr) * 64 + sg * 8 + 4);
    float4 fb0 = *(const float4*)(A + (long)(m0 + sr + 64) * 64 + sg * 8);
    float4 fb1 = *(const float4*)(A + (long)(m0 + sr + 64) * 64 + sg * 8 + 4);
    u16x8 w0 = *(const u16x8*)(WT + (long)(n0 + sr) * DTR + sg * 8);
    u16x8 w1 = *(const u16x8*)(WT + (long)(n0 + sr + 64) * DTR + sg * 8);
    u16x8 ha = {f2bf(fa0.x), f2bf(fa0.y), f2bf(fa0.z), f2bf(fa0.w),
                f2bf(fa1.x), f2bf(fa1.y), f2bf(fa1.z), f2bf(fa1.w)};
    u16x8 hb = {f2bf(fb0.x), f2bf(fb0.y), f2bf(fb0.z), f2bf(fb0.w),
                f2bf(fb1.x), f2bf(fb1.y), f2bf(fb1.z), f2bf(fb1.w)};
    *(u16x8*)(As + sr * 32 + slot * 8) = ha;
    *(u16x8*)(As + (sr + 64) * 32 + slot * 8) = hb;
    *(u16x8*)(Bs + sr * 32 + slot * 8) = w0;
    *(u16x8*)(Bs + (sr + 64) * 32 + slot * 8) = w1;
  }
  __syncthreads();

  const int lane = tid & 63, w = tid >> 6;
  const int wm = w >> 1, wn = w & 1;
  const int lo = lane & 15, hi = lane >> 4;
  f32x4 acc[4][4] = {};
  bf16x8 af[4], bfr[4];
  #pragma unroll
  for (int i = 0; i < 4; ++i) {
    int r = wm * 64 + i * 16 + lo;
    af[i] = *(const bf16x8*)(As + r * 32 + (hi ^ ((r >> 1) & 3)) * 8);
  }
  #pragma unroll
  for (int j = 0; j < 4; ++j) {
    int r = wn * 64 + j * 16 + lo;
    bfr[j] = *(const bf16x8*)(Bs + r * 32 + (hi ^ ((r >> 1) & 3)) * 8);
  }
  #pragma unroll
  for (int i = 0; i < 4; ++i)
    #pragma unroll
    for (int j = 0; j < 4; ++j)
      acc[i][j] = __builtin_amdgcn_mfma_f32_16x16x32_bf16(af[i], bfr[j], acc[i][j], 0, 0, 0);

  const float* bias = biasBase + (long)(e * NL + layer) * DI;
  float* Cb = DTout + (long)b * L_SZ * DI;
  #pragma unroll
  for (int i = 0; i < 4; ++i)
    #pragma unroll
    for (int j = 0; j < 4; ++j)
      #pragma unroll
      for (int r = 0; r < 4; ++r) {
        int row = m0 + wm * 64 + i * 16 + hi * 4 + r;
        int col = n0 + wn * 64 + j * 16 + lo;
        float v = acc[i][j][r] + bias[col];
        v = (v > 20.f) ? v : log1pf(__expf(v));
        Cb[(long)row * DI + col] = v;
      }
}

// ---------------------------------------------------------------------------
// Causal depthwise conv (DC=4) + SiLU, t-blocked.
// Thread = (b, 8-timestep block, 8-channel octet). Weights loaded once,
// 11 data rows for 8 outputs (register window).
// ---------------------------------------------------------------------------
__global__ __launch_bounds__(256) void conv_silu_kernel(
    const unsigned short* __restrict__ XCP,
    const float* __restrict__ conv_w, const float* __restrict__ conv_b,
    const int* __restrict__ expert_id, int layer,
    unsigned short* __restrict__ XCbf)
{
  const int idx = blockIdx.x * 256 + threadIdx.x;   // B * (L/TPER) * 128
  const int d8 = idx & 127;
  const int tb = (idx >> 7) & (L_SZ / TPER - 1);
  const int b = idx >> 15;                          // / (128 * 256)
  const int eid = expert_id[b];
  if (eid == 0) return;
  const int e = min(max(eid - 1, 0), NE - 1);
  const int d0 = d8 * 8;
  const int t0 = tb * TPER;

  // weights: 8 channels x 4 taps (vectorized)
  const float* cwp = conv_w + ((long)(e * NL + layer) * DI + d0) * DC;
  float4 w4[8];
  #pragma unroll
  for (int j = 0; j < 8; ++j) w4[j] = *(const float4*)(cwp + j * 4);
  float cb[8];
  {
    const float* cbp = conv_b + (long)(e * NL + layer) * DI + d0;
    float4 c0 = *(const float4*)(cbp);
    float4 c1 = *(const float4*)(cbp + 4);
    cb[0] = c0.x; cb[1] = c0.y; cb[2] = c0.z; cb[3] = c0.w;
    cb[4] = c1.x; cb[5] = c1.y; cb[6] = c1.z; cb[7] = c1.w;
  }

  const unsigned short* base = XCP + ((long)b * L_SZ + t0) * DI + d0;
  u16x8 r[TPER + 3];
  #pragma unroll
  for (int i = 0; i < TPER + 3; ++i) {
    if (t0 - 3 + i < 0) {
      u16x8 z = {0, 0, 0, 0, 0, 0, 0, 0};
      r[i] = z;
    } else {
      r[i] = *(const u16x8*)(base + (long)(i - 3) * DI);
    }
  }

  unsigned short* ob = XCbf + ((long)b * L_SZ + t0) * DI + d0;
  #pragma unroll
  for (int j = 0; j < TPER; ++j) {
    u16x8 o;
    #pragma unroll
    for (int ch = 0; ch < 8; ++ch) {
      float acc = cb[ch];
      acc = fmaf(bf2f(r[j + 0][ch]), w4[ch].x, acc);
      acc = fmaf(bf2f(r[j + 1][ch]), w4[ch].y, acc);
      acc = fmaf(bf2f(r[j + 2][ch]), w4[ch].z, acc);
      acc = fmaf(bf2f(r[j + 3][ch]), w4[ch].w, acc);
      float v = acc / (1.f + __expf(-acc));
      o[ch] = f2bf(v);
    }
    *(u16x8*)(ob + (long)j * DI) = o;
  }
}

// ---------------------------------------------------------------------------
// Chunked scan pass 1: local scan from h=0 -> Hws (h_end), Sws (sum dt).
// ---------------------------------------------------------------------------
__global__ __launch_bounds__(256) void scan_p1(
    const float* __restrict__ DTb, const unsigned short* __restrict__ XCbf,
    const float* __restrict__ PR, const float* __restrict__ A_log,
    const int* __restrict__ expert_id, int layer,
    float* __restrict__ Hws, float* __restrict__ Sws)
{
  const int b = blockIdx.z, c = blockIdx.y;
  const int eid = expert_id[b];
  if (eid == 0) return;
  const int e = min(max(eid - 1, 0), NE - 1);
  const int d = blockIdx.x * 256 + threadIdx.x;
  const int t0 = c * TC2;

  __shared__ float sB[TC2][16];
  const float* prb = PR + (long)b * L_SZ * 64;
  for (int i = threadIdx.x; i < TC2 * 16; i += 256) {
    int t = i >> 4, s = i & 15;
    sB[t][s] = prb[(long)(t0 + t) * 64 + DTR + s];
  }

  float Aval[16];
  const float* al = A_log + ((long)(e * NL + layer) * DI + d) * DS;
  #pragma unroll
  for (int s = 0; s < 16; ++s) Aval[s] = -__expf(al[s]);
  bool geo = true;
  #pragma unroll
  for (int s = 1; s < 16; ++s)
    geo = geo && (fabsf(Aval[s] - Aval[0] * (s + 1)) <= 1e-4f * (s + 1));

  float h[16];
  #pragma unroll
  for (int s = 0; s < 16; ++s) h[s] = 0.f;
  float S = 0.f;

  const float* dtp = DTb + ((long)b * L_SZ + t0) * DI + d;
  const unsigned short* xcp = XCbf + ((long)b * L_SZ + t0) * DI + d;
  __syncthreads();

  if (geo) {
    const float A0 = Aval[0];
    for (int t = 0; t < TC2; ++t) {
      float dt = dtp[(long)t * DI];
      float xc = bf2f(xcp[(long)t * DI]);
      S += dt;
      float dx = dt * xc;
      float4 b0 = *(const float4*)&sB[t][0];
      float4 b1 = *(const float4*)&sB[t][4];
      float4 b2 = *(const float4*)&sB[t][8];
      float4 b3 = *(const float4*)&sB[t][12];
      float bv[16] = {b0.x, b0.y, b0.z, b0.w, b1.x, b1.y, b1.z, b1.w,
                      b2.x, b2.y, b2.z, b2.w, b3.x, b3.y, b3.z, b3.w};
      float g = __expf(dt * A0);
      float ee = g;
      #pragma unroll
      for (int s = 0; s < 16; ++s) {
        h[s] = fmaf(ee, h[s], dx * bv[s]);
        ee *= g;
      }
    }
  } else {
    for (int t = 0; t < TC2; ++t) {
      float dt = dtp[(long)t * DI];
      float xc = bf2f(xcp[(long)t * DI]);
      S += dt;
      float dx = dt * xc;
      float4 b0 = *(const float4*)&sB[t][0];
      float4 b1 = *(const float4*)&sB[t][4];
      float4 b2 = *(const float4*)&sB[t][8];
      float4 b3 = *(const float4*)&sB[t][12];
      float bv[16] = {b0.x, b0.y, b0.z, b0.w, b1.x, b1.y, b1.z, b1.w,
                      b2.x, b2.y, b2.z, b2.w, b3.x, b3.y, b3.z, b3.w};
      #pragma unroll
      for (int s = 0; s < 16; ++s)
        h[s] = fmaf(__expf(dt * Aval[s]), h[s], dx * bv[s]);
    }
  }

  const long hoff = (((long)b * NCH + c) * DI + d) * 16;
  #pragma unroll
  for (int s = 0; s < 16; s += 4)
    *(float4*)&Hws[hoff + s] = make_float4(h[s], h[s + 1], h[s + 2], h[s + 3]);
  Sws[((long)b * NCH + c) * DI + d] = S;
}

// ---------------------------------------------------------------------------
// Chunk combine (in-place): Hws[c] := h_in(c)
// ---------------------------------------------------------------------------
__global__ __launch_bounds__(256) void scan_combine(
    float* __restrict__ Hws, const float* __restrict__ Sws,
    const float* __restrict__ A_log,
    const int* __restrict__ expert_id, int layer)
{
  const int gid = blockIdx.x * 256 + threadIdx.x;
  const int s = gid & 15;
  const int d = (gid >> 4) & (DI - 1);
  const int b = gid >> 14;
  const int eid = expert_id[b];
  if (eid == 0) return;
  const int e = min(max(eid - 1, 0), NE - 1);
  const float Aval = -__expf(A_log[((long)(e * NL + layer) * DI + d) * DS + s]);
  float h = 0.f;
  for (int c = 0; c < NCH; ++c) {
    const long off = (((long)b * NCH + c) * DI + d) * 16 + s;
    float q = Hws[off];
    float Sc = Sws[((long)b * NCH + c) * DI + d];
    Hws[off] = h;
    h = fmaf(__expf(Aval * Sc), h, q);
  }
}

// ---------------------------------------------------------------------------
// Chunked scan pass 2: re-scan seeded with h_in; y=(h@C + D*xc)*silu(res) -> bf16
// ---------------------------------------------------------------------------
__global__ __launch_bounds__(256) void scan_p2(
    const float* __restrict__ DTb, const unsigned short* __restrict__ XCbf,
    const unsigned short* __restrict__ RESb, const float* __restrict__ PR,
    const float* __restrict__ A_log, const float* __restrict__ Dw,
    const float* __restrict__ Hws,
    const int* __restrict__ expert_id, int layer,
    unsigned short* __restrict__ Ybf)
{
  const int b = blockIdx.z, c = blockIdx.y;
  const int eid = expert_id[b];
  if (eid == 0) return;
  const int e = min(max(eid - 1, 0), NE - 1);
  const int d = blockIdx.x * 256 + threadIdx.x;
  const int t0 = c * TC2;

  __shared__ float sBC[TC2][32];
  const float* prb = PR + (long)b * L_SZ * 64;
  for (int i = threadIdx.x; i < TC2 * 32; i += 256) {
    int t = i >> 5, j = i & 31;
    sBC[t][j] = prb[(long)(t0 + t) * 64 + DTR + j];
  }

  float Aval[16];
  const float* al = A_log + ((long)(e * NL + layer) * DI + d) * DS;
  #pragma unroll
  for (int s = 0; s < 16; ++s) Aval[s] = -__expf(al[s]);
  bool geo = true;
  #pragma unroll
  for (int s = 1; s < 16; ++s)
    geo = geo && (fabsf(Aval[s] - Aval[0] * (s + 1)) <= 1e-4f * (s + 1));

  float h[16];
  const long hoff = (((long)b * NCH + c) * DI + d) * 16;
  #pragma unroll
  for (int s = 0; s < 16; s += 4) {
    float4 hv = *(const float4*)&Hws[hoff + s];
    h[s] = hv.x; h[s + 1] = hv.y; h[s + 2] = hv.z; h[s + 3] = hv.w;
  }
  const float Dd = Dw[(long)(e * NL + layer) * DI + d];

  const float* dtp = DTb + ((long)b * L_SZ + t0) * DI + d;
  const unsigned short* xcp = XCbf + ((long)b * L_SZ + t0) * DI + d;
  const unsigned short* rsp = RESb + ((long)b * L_SZ + t0) * DI + d;
  unsigned short* yb = Ybf + ((long)b * L_SZ + t0) * DI + d;
  __syncthreads();

  const float A0 = Aval[0];
  for (int t = 0; t < TC2; ++t) {
    float dt  = dtp[(long)t * DI];
    float res = bf2f(rsp[(long)t * DI]);
    float xc  = bf2f(xcp[(long)t * DI]);
    float dx = dt * xc;
    float4 b0 = *(const float4*)&sBC[t][0];
    float4 b1 = *(const float4*)&sBC[t][4];
    float4 b2 = *(const float4*)&sBC[t][8];
    float4 b3 = *(const float4*)&sBC[t][12];
    float4 c0 = *(const float4*)&sBC[t][16];
    float4 c1 = *(const float4*)&sBC[t][20];
    float4 c2 = *(const float4*)&sBC[t][24];
    float4 c3 = *(const float4*)&sBC[t][28];
    float bv[16] = {b0.x, b0.y, b0.z, b0.w, b1.x, b1.y, b1.z, b1.w,
                    b2.x, b2.y, b2.z, b2.w, b3.x, b3.y, b3.z, b3.w};
    float cv[16] = {c0.x, c0.y, c0.z, c0.w, c1.x, c1.y, c1.z, c1.w,
                    c2.x, c2.y, c2.z, c2.w, c3.x, c3.y, c3.z, c3.w};
    float y = 0.f;
    if (geo) {
      float g = __expf(dt * A0);
      float ee = g;
      #pragma unroll
      for (int s = 0; s < 16; ++s) {
        h[s] = fmaf(ee, h[s], dx * bv[s]);
        y = fmaf(h[s], cv[s], y);
        ee *= g;
      }
    } else {
      #pragma unroll
      for (int s = 0; s < 16; ++s) {
        h[s] = fmaf(__expf(dt * Aval[s]), h[s], dx * bv[s]);
        y = fmaf(h[s], cv[s], y);
      }
    }
    y = fmaf(Dd, xc, y);
    float sil = res / (1.f + __expf(-res));
    yb[(long)t * DI] = f2bf(y * sil);
  }
}

// ---------------------------------------------------------------------------
extern "C" void kernel_launch(void* const* d_in, const int* in_sizes, int n_in,
                              void* d_out, int out_size, void* d_ws, size_t ws_size,
                              hipStream_t stream)
{
  const float* x      = (const float*)d_in[0];
  const int*   eidp   = (const int*)d_in[1];
  const float* W_in   = (const float*)d_in[2];
  const float* conv_w = (const float*)d_in[3];
  const float* conv_b = (const float*)d_in[4];
  const float* W_x    = (const float*)d_in[5];
  const float* W_dt   = (const float*)d_in[6];
  const float* b_dt   = (const float*)d_in[7];
  const float* A_log  = (const float*)d_in[8];
  const float* Dw     = (const float*)d_in[9];
  const float* W_out  = (const float*)d_in[10];
  float* out = (float*)d_out;
  float* ws  = (float*)d_ws;

  // workspace layout — total 251,133,952 B (< proven-safe 265.8 MB)
  float* DT  = ws;                          // 16,777,216 f32 (64 MB)
  float* PR  = DT + 16777216L;              //  1,048,576 f32 ( 4 MB)
  float* Hws = PR + 1048576L;               //  8,388,608 f32 (32 MB)
  float* Sws = Hws + 8388608L;              //    524,288 f32 ( 2 MB)
  unsigned short* XCP  = (unsigned short*)(Sws + 524288L);  // 16.8M bf16 (32 MB)
  unsigned short* Ybf  = XCP;                               // overlay (disjoint liveness)
  unsigned short* XCbf = XCP + 16777216L;                   // 32 MB
  unsigned short* RESb = XCbf + 16777216L;                  // 32 MB
  unsigned short* XB   = RESb + 16777216L;                  // 16 MB (x shadow / XN)
  unsigned short* WinT  = XB + 8388608L;                    // 16 MB [p][2048][512]
  unsigned short* WoutT = WinT + 8388608L;                  //  8 MB [p][512][1024]
  unsigned short* WxT   = WoutT + 4194304L;                 //  1 MB [p][64][1024]
  unsigned short* WdtT  = WxT + 524288L;                    // 0.5 MB [p][1024][32]

  transpose_w_kernel<<<dim3(2 * DI / 32, DM / 32, NE * NL), 256, 0, stream>>>(
      W_in, WinT, DM, 2 * DI);
  transpose_w_kernel<<<dim3(DM / 32, DI / 32, NE * NL), 256, 0, stream>>>(
      W_out, WoutT, DI, DM);
  transpose_w_kernel<<<dim3(2, DI / 32, NE * NL), 256, 0, stream>>>(
      W_x, WxT, DI, 64);
  transpose_w_kernel<<<dim3(DI / 32, 1, NE * NL), 256, 0, stream>>>(
      W_dt, WdtT, DTR, DI);
  f2bf_kernel<<<8192, 256, 0, stream>>>(x, XB);   // 8.4M elems / 4 per thread

  for (int l = 0; l < NL; ++l) {
    // 1) xr = xin @ W_in  (M=2048 N=2048 K=512): split -> XCP bf16 | RESb bf16
    gemm_bf16<3, 128, 128><<<dim3(2 * DI / 128, L_SZ / 128, B_SZ), 256, 0, stream>>>(
        XB, (long)L_SZ * DM, DM, DM, WinT, (long)(2 * DI) * DM,
        nullptr, eidp, l, nullptr, XCP, RESb, 0, (long)L_SZ * DI);

    // 2) conv + silu -> XCbf bf16  (t-blocked, weights amortized)
    conv_silu_kernel<<<B_SZ * (L_SZ / TPER) * 128 / 256, 256, 0, stream>>>(
        XCP, conv_w, conv_b, eidp, l, XCbf);

    // 3) proj = xc @ W_x -> PR fp32  (M=2048 N=64 K=1024, TM=TN=64)
    gemm_bf16<0, 64, 64><<<dim3(1, L_SZ / 64, B_SZ), 256, 0, stream>>>(
        XCbf, (long)L_SZ * DI, DI, DI, WxT, (long)64 * DI,
        nullptr, eidp, l, PR, nullptr, nullptr, 64, (long)L_SZ * 64);

    // 4) dt = softplus(PR[:,:32] @ W_dt + b_dt) -> DT fp32
    gemm_dt<<<dim3(DI / 128, L_SZ / 128, B_SZ), 256, 0, stream>>>(
        PR, WdtT, b_dt, eidp, l, DT);

    // 5) chunked scan -> Ybf bf16 (overlays XCP, dead after conv)
    scan_p1<<<dim3(DI / 256, NCH, B_SZ), 256, 0, stream>>>(
        DT, XCbf, PR, A_log, eidp, l, Hws, Sws);
    scan_combine<<<(B_SZ * DI * DS) / 256, 256, 0, stream>>>(
        Hws, Sws, A_log, eidp, l);
    scan_p2<<<dim3(DI / 256, NCH, B_SZ), 256, 0, stream>>>(
        DT, XCbf, RESb, PR, A_log, Dw, Hws, eidp, l, Ybf);

    // 6) y @ W_out  (M=2048 N=512 K=1024)
    if (l == NL - 1) {
      gemm_bf16<2, 128, 128><<<dim3(DM / 128, L_SZ / 128, B_SZ), 256, 0, stream>>>(
          Ybf, (long)L_SZ * DI, DI, DI, WoutT, (long)DM * DI,
          x, eidp, l, out, nullptr, nullptr, DM, (long)L_SZ * DM);
    } else {
      gemm_bf16<4, 128, 128><<<dim3(DM / 128, L_SZ / 128, B_SZ), 256, 0, stream>>>(
          Ybf, (long)L_SZ * DI, DI, DI, WoutT, (long)DM * DI,
          nullptr, eidp, l, nullptr, XB, nullptr, DM, (long)L_SZ * DM);
    }
  }
}

// Round 7
// 444.564 us; speedup vs baseline: 5.4391x; 1.2021x over previous
//
#include <hip/hip_runtime.h>
#include <hip/hip_bf16.h>
#include <cmath>

#define B_SZ 8
#define L_SZ 2048
#define DM 512
#define DI 1024
#define DS 16
#define DC 4
#define DTR 32
#define NE 4
#define NL 2
#define NCH 64
#define TC2 32   // timesteps per chunk = L_SZ / NCH
#define TPER 8   // timesteps per conv thread

typedef __attribute__((ext_vector_type(8))) short bf16x8;
typedef __attribute__((ext_vector_type(8))) unsigned short u16x8;
typedef __attribute__((ext_vector_type(4))) float f32x4;

__device__ __forceinline__ unsigned short f2bf(float x) {
  __hip_bfloat16 h = __float2bfloat16(x);
  return __builtin_bit_cast(unsigned short, h);
}
__device__ __forceinline__ float bf2f(unsigned short u) {
  return __builtin_bit_cast(float, (unsigned)u << 16);
}

// async global(16B/lane) -> LDS (wave-uniform base + lane*16)
__device__ __forceinline__ void glds16(const unsigned short* g, unsigned short* l) {
  __builtin_amdgcn_global_load_lds(
      (const __attribute__((address_space(1))) unsigned int*)g,
      (__attribute__((address_space(3))) unsigned int*)l, 16, 0, 0);
}

// fast softplus: hardware exp/log; exact enough under bf16 storage
__device__ __forceinline__ float softplus_fast(float v) {
  return (v > 20.f) ? v : __logf(1.f + __expf(v));
}

// ---------------------------------------------------------------------------
// Transpose + fp32->bf16: in fp32 [P][R][C] -> out bf16 [P][C][R]
// ---------------------------------------------------------------------------
__global__ __launch_bounds__(256) void transpose_w_kernel(
    const float* __restrict__ in, unsigned short* __restrict__ out, int R, int C)
{
  __shared__ float t[32][33];
  const int p = blockIdx.z;
  const int r0 = blockIdx.y * 32, c0 = blockIdx.x * 32;
  const int tx = threadIdx.x & 31, ty = threadIdx.x >> 5;
  const float* ip = in + (long)p * R * C;
  unsigned short* op = out + (long)p * R * C;
  #pragma unroll
  for (int i = 0; i < 32; i += 8)
    t[ty + i][tx] = ip[(long)(r0 + ty + i) * C + c0 + tx];
  __syncthreads();
  #pragma unroll
  for (int i = 0; i < 32; i += 8)
    op[(long)(c0 + ty + i) * R + r0 + tx] = f2bf(t[tx][ty + i]);
}

// fp32 -> bf16 elementwise (x shadow)
__global__ __launch_bounds__(256) void f2bf_kernel(
    const float* __restrict__ in, unsigned short* __restrict__ out)
{
  long i = ((long)blockIdx.x * 256 + threadIdx.x) * 4;
  float4 v = *(const float4*)(in + i);
  out[i + 0] = f2bf(v.x); out[i + 1] = f2bf(v.y);
  out[i + 2] = f2bf(v.z); out[i + 3] = f2bf(v.w);
}

// ---------------------------------------------------------------------------
// bf16 MFMA GEMM with global_load_lds staging (m97 structure).
// A bf16 [M][lda], WT bf16 [N][K]. Tile TM x TN (each 64 or 128), BK=32,
// 4 waves (2x2).
// EPI 0: fp32 store to Cf.
// EPI 2: fp32 store + eid==0 passthrough of x.
// EPI 3: split: col<DI -> bf16 Cbh, else -> bf16 Cbh2 at col-DI (both ld DI).
// EPI 4: bf16 store to Cbh.
// ---------------------------------------------------------------------------
template<int EPI, int TM, int TN>
__global__ __launch_bounds__(256) void gemm_bf16(
    const unsigned short* __restrict__ Abase, long aBatch, int K, int lda,
    const unsigned short* __restrict__ WTbase, long wStride,
    const float* __restrict__ xpass,
    const int* __restrict__ expert_id, int layer,
    float* __restrict__ Cf, unsigned short* __restrict__ Cbh,
    unsigned short* __restrict__ Cbh2,
    int ldc, long cBatch)
{
  constexpr int IF = TM / 32;      // M-frags per wave
  constexpr int JF = TN / 32;      // N-frags per wave
  constexpr int AST = TM / 4;      // A rows staged per wave
  constexpr int BST = TN / 4;      // B rows staged per wave

  const int b = blockIdx.z;
  const int eid = expert_id[b];
  const int m0 = blockIdx.y * TM, n0 = blockIdx.x * TN;
  const int tid = threadIdx.x;

  if (eid == 0) {
    if (EPI == 2) {
      float* Co = Cf + (long)b * cBatch;
      const float* xp = xpass + (long)b * L_SZ * DM;
      for (int i = tid; i < TM * TN; i += 256) {
        int r = m0 + (i / TN), c = n0 + (i % TN);
        Co[(long)r * ldc + c] = xp[(long)r * DM + c];
      }
    }
    return;
  }
  const int e = min(max(eid - 1, 0), NE - 1);
  const unsigned short* A = Abase + (long)b * aBatch;
  const unsigned short* WT = WTbase + (long)(e * NL + layer) * wStride;

  __shared__ unsigned short As[TM * 32];
  __shared__ unsigned short Bs[TN * 32];

  const int w = tid >> 6, lane = tid & 63;
  const int srow = lane >> 2;          // 0..15
  const int sk = (lane & 3) * 8;       // ushort offset in K

  // A: wave w stages rows [w*AST, (w+1)*AST) in 16-row chunks
  const unsigned short* aG0 = A + (long)(m0 + w * AST + srow) * lda + sk;
  const unsigned short* aG1 = aG0 + 16 * lda;         // used iff AST==32
  unsigned short* aL0 = As + (w * AST) * 32;
  unsigned short* aL1 = As + (w * AST + 16) * 32;
  const unsigned short* bG0 = WT + (long)(n0 + w * BST + srow) * K + sk;
  const unsigned short* bG1 = bG0 + 16 * K;           // used iff BST==32
  unsigned short* bL0 = Bs + (w * BST) * 32;
  unsigned short* bL1 = Bs + (w * BST + 16) * 32;

  const int wm = w >> 1, wn = w & 1;
  const int lo = lane & 15, hi = lane >> 4;
  int aoff[IF], boff[JF];
  #pragma unroll
  for (int i = 0; i < IF; ++i)
    aoff[i] = (wm * (TM / 2) + i * 16 + lo) * 32 + hi * 8;
  #pragma unroll
  for (int j = 0; j < JF; ++j)
    boff[j] = (wn * (TN / 2) + j * 16 + lo) * 32 + hi * 8;

  f32x4 acc[IF][JF] = {};

  for (int k0 = 0; k0 < K; k0 += 32) {
    glds16(aG0 + k0, aL0);
    if (AST == 32) glds16(aG1 + k0, aL1);
    glds16(bG0 + k0, bL0);
    if (BST == 32) glds16(bG1 + k0, bL1);
    __syncthreads();

    bf16x8 af[IF], bfr[JF];
    #pragma unroll
    for (int i = 0; i < IF; ++i) af[i] = *(const bf16x8*)(As + aoff[i]);
    #pragma unroll
    for (int j = 0; j < JF; ++j) bfr[j] = *(const bf16x8*)(Bs + boff[j]);
    #pragma unroll
    for (int i = 0; i < IF; ++i)
      #pragma unroll
      for (int j = 0; j < JF; ++j)
        acc[i][j] = __builtin_amdgcn_mfma_f32_16x16x32_bf16(af[i], bfr[j], acc[i][j], 0, 0, 0);
    __syncthreads();
  }

  // epilogue: D layout col=lane&15, row=(lane>>4)*4+r
  #pragma unroll
  for (int i = 0; i < IF; ++i) {
    #pragma unroll
    for (int j = 0; j < JF; ++j) {
      #pragma unroll
      for (int r = 0; r < 4; ++r) {
        int row = m0 + wm * (TM / 2) + i * 16 + hi * 4 + r;
        int col = n0 + wn * (TN / 2) + j * 16 + lo;
        float v = acc[i][j][r];
        if (EPI == 0 || EPI == 2) {
          (Cf + (long)b * cBatch)[(long)row * ldc + col] = v;
        } else if (EPI == 4) {
          (Cbh + (long)b * cBatch)[(long)row * ldc + col] = f2bf(v);
        } else {  // EPI 3: split xc | res, both bf16
          if (col < DI)
            (Cbh + (long)b * cBatch)[(long)row * DI + col] = f2bf(v);
          else
            (Cbh2 + (long)b * cBatch)[(long)row * DI + (col - DI)] = f2bf(v);
        }
      }
    }
  }
}

// ---------------------------------------------------------------------------
// dt GEMM (fp32 A, K=32): DT = softplus(PR[:, :32] @ W_dt + b_dt), bf16 out.
// ---------------------------------------------------------------------------
__global__ __launch_bounds__(256) void gemm_dt(
    const float* __restrict__ PRb, const unsigned short* __restrict__ WTbase,
    const float* __restrict__ biasBase,
    const int* __restrict__ expert_id, int layer,
    unsigned short* __restrict__ DTout)
{
  const int b = blockIdx.z;
  const int eid = expert_id[b];
  if (eid == 0) return;
  const int e = min(max(eid - 1, 0), NE - 1);
  const int m0 = blockIdx.y * 128, n0 = blockIdx.x * 128;
  const int tid = threadIdx.x;
  const float* A = PRb + (long)b * L_SZ * 64;
  const unsigned short* WT = WTbase + (long)(e * NL + layer) * DI * DTR;

  __shared__ unsigned short As[128 * 32];
  __shared__ unsigned short Bs[128 * 32];

  const int sr = tid >> 2, sg = tid & 3;
  const int slot = sg ^ ((sr >> 1) & 3);

  {
    float4 fa0 = *(const float4*)(A + (long)(m0 + sr) * 64 + sg * 8);
    float4 fa1 = *(const float4*)(A + (long)(m0 + sr) * 64 + sg * 8 + 4);
    float4 fb0 = *(const float4*)(A + (long)(m0 + sr + 64) * 64 + sg * 8);
    float4 fb1 = *(const float4*)(A + (long)(m0 + sr + 64) * 64 + sg * 8 + 4);
    u16x8 w0 = *(const u16x8*)(WT + (long)(n0 + sr) * DTR + sg * 8);
    u16x8 w1 = *(const u16x8*)(WT + (long)(n0 + sr + 64) * DTR + sg * 8);
    u16x8 ha = {f2bf(fa0.x), f2bf(fa0.y), f2bf(fa0.z), f2bf(fa0.w),
                f2bf(fa1.x), f2bf(fa1.y), f2bf(fa1.z), f2bf(fa1.w)};
    u16x8 hb = {f2bf(fb0.x), f2bf(fb0.y), f2bf(fb0.z), f2bf(fb0.w),
                f2bf(fb1.x), f2bf(fb1.y), f2bf(fb1.z), f2bf(fb1.w)};
    *(u16x8*)(As + sr * 32 + slot * 8) = ha;
    *(u16x8*)(As + (sr + 64) * 32 + slot * 8) = hb;
    *(u16x8*)(Bs + sr * 32 + slot * 8) = w0;
    *(u16x8*)(Bs + (sr + 64) * 32 + slot * 8) = w1;
  }
  __syncthreads();

  const int lane = tid & 63, w = tid >> 6;
  const int wm = w >> 1, wn = w & 1;
  const int lo = lane & 15, hi = lane >> 4;
  f32x4 acc[4][4] = {};
  bf16x8 af[4], bfr[4];
  #pragma unroll
  for (int i = 0; i < 4; ++i) {
    int r = wm * 64 + i * 16 + lo;
    af[i] = *(const bf16x8*)(As + r * 32 + (hi ^ ((r >> 1) & 3)) * 8);
  }
  #pragma unroll
  for (int j = 0; j < 4; ++j) {
    int r = wn * 64 + j * 16 + lo;
    bfr[j] = *(const bf16x8*)(Bs + r * 32 + (hi ^ ((r >> 1) & 3)) * 8);
  }
  #pragma unroll
  for (int i = 0; i < 4; ++i)
    #pragma unroll
    for (int j = 0; j < 4; ++j)
      acc[i][j] = __builtin_amdgcn_mfma_f32_16x16x32_bf16(af[i], bfr[j], acc[i][j], 0, 0, 0);

  const float* bias = biasBase + (long)(e * NL + layer) * DI;
  unsigned short* Cb = DTout + (long)b * L_SZ * DI;
  #pragma unroll
  for (int i = 0; i < 4; ++i)
    #pragma unroll
    for (int j = 0; j < 4; ++j)
      #pragma unroll
      for (int r = 0; r < 4; ++r) {
        int row = m0 + wm * 64 + i * 16 + hi * 4 + r;
        int col = n0 + wn * 64 + j * 16 + lo;
        float v = softplus_fast(acc[i][j][r] + bias[col]);
        Cb[(long)row * DI + col] = f2bf(v);
      }
}

// ---------------------------------------------------------------------------
// Causal depthwise conv (DC=4) + SiLU, t-blocked.
// Thread = (b, 8-timestep block, 8-channel octet). Weights loaded once,
// 11 data rows for 8 outputs (register window).
// ---------------------------------------------------------------------------
__global__ __launch_bounds__(256) void conv_silu_kernel(
    const unsigned short* __restrict__ XCP,
    const float* __restrict__ conv_w, const float* __restrict__ conv_b,
    const int* __restrict__ expert_id, int layer,
    unsigned short* __restrict__ XCbf)
{
  const int idx = blockIdx.x * 256 + threadIdx.x;   // B * (L/TPER) * 128
  const int d8 = idx & 127;
  const int tb = (idx >> 7) & (L_SZ / TPER - 1);
  const int b = idx >> 15;                          // / (128 * 256)
  const int eid = expert_id[b];
  if (eid == 0) return;
  const int e = min(max(eid - 1, 0), NE - 1);
  const int d0 = d8 * 8;
  const int t0 = tb * TPER;

  // weights: 8 channels x 4 taps (vectorized)
  const float* cwp = conv_w + ((long)(e * NL + layer) * DI + d0) * DC;
  float4 w4[8];
  #pragma unroll
  for (int j = 0; j < 8; ++j) w4[j] = *(const float4*)(cwp + j * 4);
  float cb[8];
  {
    const float* cbp = conv_b + (long)(e * NL + layer) * DI + d0;
    float4 c0 = *(const float4*)(cbp);
    float4 c1 = *(const float4*)(cbp + 4);
    cb[0] = c0.x; cb[1] = c0.y; cb[2] = c0.z; cb[3] = c0.w;
    cb[4] = c1.x; cb[5] = c1.y; cb[6] = c1.z; cb[7] = c1.w;
  }

  const unsigned short* base = XCP + ((long)b * L_SZ + t0) * DI + d0;
  u16x8 r[TPER + 3];
  #pragma unroll
  for (int i = 0; i < TPER + 3; ++i) {
    if (t0 - 3 + i < 0) {
      u16x8 z = {0, 0, 0, 0, 0, 0, 0, 0};
      r[i] = z;
    } else {
      r[i] = *(const u16x8*)(base + (long)(i - 3) * DI);
    }
  }

  unsigned short* ob = XCbf + ((long)b * L_SZ + t0) * DI + d0;
  #pragma unroll
  for (int j = 0; j < TPER; ++j) {
    u16x8 o;
    #pragma unroll
    for (int ch = 0; ch < 8; ++ch) {
      float acc = cb[ch];
      acc = fmaf(bf2f(r[j + 0][ch]), w4[ch].x, acc);
      acc = fmaf(bf2f(r[j + 1][ch]), w4[ch].y, acc);
      acc = fmaf(bf2f(r[j + 2][ch]), w4[ch].z, acc);
      acc = fmaf(bf2f(r[j + 3][ch]), w4[ch].w, acc);
      float v = acc / (1.f + __expf(-acc));
      o[ch] = f2bf(v);
    }
    *(u16x8*)(ob + (long)j * DI) = o;
  }
}

// ---------------------------------------------------------------------------
// Chunked scan pass 1: local scan from h=0 -> Hws (h_end), Sws (sum dt).
// ---------------------------------------------------------------------------
__global__ __launch_bounds__(256) void scan_p1(
    const unsigned short* __restrict__ DTb, const unsigned short* __restrict__ XCbf,
    const float* __restrict__ PR, const float* __restrict__ A_log,
    const int* __restrict__ expert_id, int layer,
    float* __restrict__ Hws, float* __restrict__ Sws)
{
  const int b = blockIdx.z, c = blockIdx.y;
  const int eid = expert_id[b];
  if (eid == 0) return;
  const int e = min(max(eid - 1, 0), NE - 1);
  const int d = blockIdx.x * 256 + threadIdx.x;
  const int t0 = c * TC2;

  __shared__ float sB[TC2][16];
  const float* prb = PR + (long)b * L_SZ * 64;
  for (int i = threadIdx.x; i < TC2 * 16; i += 256) {
    int t = i >> 4, s = i & 15;
    sB[t][s] = prb[(long)(t0 + t) * 64 + DTR + s];
  }

  float Aval[16];
  const float* al = A_log + ((long)(e * NL + layer) * DI + d) * DS;
  #pragma unroll
  for (int s = 0; s < 16; ++s) Aval[s] = -__expf(al[s]);
  bool geo = true;
  #pragma unroll
  for (int s = 1; s < 16; ++s)
    geo = geo && (fabsf(Aval[s] - Aval[0] * (s + 1)) <= 1e-4f * (s + 1));

  float h[16];
  #pragma unroll
  for (int s = 0; s < 16; ++s) h[s] = 0.f;
  float S = 0.f;

  const unsigned short* dtp = DTb + ((long)b * L_SZ + t0) * DI + d;
  const unsigned short* xcp = XCbf + ((long)b * L_SZ + t0) * DI + d;
  __syncthreads();

  if (geo) {
    const float A0 = Aval[0];
    for (int t = 0; t < TC2; ++t) {
      float dt = bf2f(dtp[(long)t * DI]);
      float xc = bf2f(xcp[(long)t * DI]);
      S += dt;
      float dx = dt * xc;
      float4 b0 = *(const float4*)&sB[t][0];
      float4 b1 = *(const float4*)&sB[t][4];
      float4 b2 = *(const float4*)&sB[t][8];
      float4 b3 = *(const float4*)&sB[t][12];
      float bv[16] = {b0.x, b0.y, b0.z, b0.w, b1.x, b1.y, b1.z, b1.w,
                      b2.x, b2.y, b2.z, b2.w, b3.x, b3.y, b3.z, b3.w};
      float g = __expf(dt * A0);
      float ee = g;
      #pragma unroll
      for (int s = 0; s < 16; ++s) {
        h[s] = fmaf(ee, h[s], dx * bv[s]);
        ee *= g;
      }
    }
  } else {
    for (int t = 0; t < TC2; ++t) {
      float dt = bf2f(dtp[(long)t * DI]);
      float xc = bf2f(xcp[(long)t * DI]);
      S += dt;
      float dx = dt * xc;
      float4 b0 = *(const float4*)&sB[t][0];
      float4 b1 = *(const float4*)&sB[t][4];
      float4 b2 = *(const float4*)&sB[t][8];
      float4 b3 = *(const float4*)&sB[t][12];
      float bv[16] = {b0.x, b0.y, b0.z, b0.w, b1.x, b1.y, b1.z, b1.w,
                      b2.x, b2.y, b2.z, b2.w, b3.x, b3.y, b3.z, b3.w};
      #pragma unroll
      for (int s = 0; s < 16; ++s)
        h[s] = fmaf(__expf(dt * Aval[s]), h[s], dx * bv[s]);
    }
  }

  const long hoff = (((long)b * NCH + c) * DI + d) * 16;
  #pragma unroll
  for (int s = 0; s < 16; s += 4)
    *(float4*)&Hws[hoff + s] = make_float4(h[s], h[s + 1], h[s + 2], h[s + 3]);
  Sws[((long)b * NCH + c) * DI + d] = S;
}

// ---------------------------------------------------------------------------
// Chunk combine (in-place): Hws[c] := h_in(c)
// ---------------------------------------------------------------------------
__global__ __launch_bounds__(256) void scan_combine(
    float* __restrict__ Hws, const float* __restrict__ Sws,
    const float* __restrict__ A_log,
    const int* __restrict__ expert_id, int layer)
{
  const int gid = blockIdx.x * 256 + threadIdx.x;
  const int s = gid & 15;
  const int d = (gid >> 4) & (DI - 1);
  const int b = gid >> 14;
  const int eid = expert_id[b];
  if (eid == 0) return;
  const int e = min(max(eid - 1, 0), NE - 1);
  const float Aval = -__expf(A_log[((long)(e * NL + layer) * DI + d) * DS + s]);
  float h = 0.f;
  for (int c = 0; c < NCH; ++c) {
    const long off = (((long)b * NCH + c) * DI + d) * 16 + s;
    float q = Hws[off];
    float Sc = Sws[((long)b * NCH + c) * DI + d];
    Hws[off] = h;
    h = fmaf(__expf(Aval * Sc), h, q);
  }
}

// ---------------------------------------------------------------------------
// Chunked scan pass 2: re-scan seeded with h_in; y=(h@C + D*xc)*silu(res) -> bf16
// ---------------------------------------------------------------------------
__global__ __launch_bounds__(256) void scan_p2(
    const unsigned short* __restrict__ DTb, const unsigned short* __restrict__ XCbf,
    const unsigned short* __restrict__ RESb, const float* __restrict__ PR,
    const float* __restrict__ A_log, const float* __restrict__ Dw,
    const float* __restrict__ Hws,
    const int* __restrict__ expert_id, int layer,
    unsigned short* __restrict__ Ybf)
{
  const int b = blockIdx.z, c = blockIdx.y;
  const int eid = expert_id[b];
  if (eid == 0) return;
  const int e = min(max(eid - 1, 0), NE - 1);
  const int d = blockIdx.x * 256 + threadIdx.x;
  const int t0 = c * TC2;

  __shared__ float sBC[TC2][32];
  const float* prb = PR + (long)b * L_SZ * 64;
  for (int i = threadIdx.x; i < TC2 * 32; i += 256) {
    int t = i >> 5, j = i & 31;
    sBC[t][j] = prb[(long)(t0 + t) * 64 + DTR + j];
  }

  float Aval[16];
  const float* al = A_log + ((long)(e * NL + layer) * DI + d) * DS;
  #pragma unroll
  for (int s = 0; s < 16; ++s) Aval[s] = -__expf(al[s]);
  bool geo = true;
  #pragma unroll
  for (int s = 1; s < 16; ++s)
    geo = geo && (fabsf(Aval[s] - Aval[0] * (s + 1)) <= 1e-4f * (s + 1));

  float h[16];
  const long hoff = (((long)b * NCH + c) * DI + d) * 16;
  #pragma unroll
  for (int s = 0; s < 16; s += 4) {
    float4 hv = *(const float4*)&Hws[hoff + s];
    h[s] = hv.x; h[s + 1] = hv.y; h[s + 2] = hv.z; h[s + 3] = hv.w;
  }
  const float Dd = Dw[(long)(e * NL + layer) * DI + d];

  const unsigned short* dtp = DTb + ((long)b * L_SZ + t0) * DI + d;
  const unsigned short* xcp = XCbf + ((long)b * L_SZ + t0) * DI + d;
  const unsigned short* rsp = RESb + ((long)b * L_SZ + t0) * DI + d;
  unsigned short* yb = Ybf + ((long)b * L_SZ + t0) * DI + d;
  __syncthreads();

  const float A0 = Aval[0];
  for (int t = 0; t < TC2; ++t) {
    float dt  = bf2f(dtp[(long)t * DI]);
    float res = bf2f(rsp[(long)t * DI]);
    float xc  = bf2f(xcp[(long)t * DI]);
    float dx = dt * xc;
    float4 b0 = *(const float4*)&sBC[t][0];
    float4 b1 = *(const float4*)&sBC[t][4];
    float4 b2 = *(const float4*)&sBC[t][8];
    float4 b3 = *(const float4*)&sBC[t][12];
    float4 c0 = *(const float4*)&sBC[t][16];
    float4 c1 = *(const float4*)&sBC[t][20];
    float4 c2 = *(const float4*)&sBC[t][24];
    float4 c3 = *(const float4*)&sBC[t][28];
    float bv[16] = {b0.x, b0.y, b0.z, b0.w, b1.x, b1.y, b1.z, b1.w,
                    b2.x, b2.y, b2.z, b2.w, b3.x, b3.y, b3.z, b3.w};
    float cv[16] = {c0.x, c0.y, c0.z, c0.w, c1.x, c1.y, c1.z, c1.w,
                    c2.x, c2.y, c2.z, c2.w, c3.x, c3.y, c3.z, c3.w};
    float y = 0.f;
    if (geo) {
      float g = __expf(dt * A0);
      float ee = g;
      #pragma unroll
      for (int s = 0; s < 16; ++s) {
        h[s] = fmaf(ee, h[s], dx * bv[s]);
        y = fmaf(h[s], cv[s], y);
        ee *= g;
      }
    } else {
      #pragma unroll
      for (int s = 0; s < 16; ++s) {
        h[s] = fmaf(__expf(dt * Aval[s]), h[s], dx * bv[s]);
        y = fmaf(h[s], cv[s], y);
      }
    }
    y = fmaf(Dd, xc, y);
    float sil = res / (1.f + __expf(-res));
    yb[(long)t * DI] = f2bf(y * sil);
  }
}

// ---------------------------------------------------------------------------
extern "C" void kernel_launch(void* const* d_in, const int* in_sizes, int n_in,
                              void* d_out, int out_size, void* d_ws, size_t ws_size,
                              hipStream_t stream)
{
  const float* x      = (const float*)d_in[0];
  const int*   eidp   = (const int*)d_in[1];
  const float* W_in   = (const float*)d_in[2];
  const float* conv_w = (const float*)d_in[3];
  const float* conv_b = (const float*)d_in[4];
  const float* W_x    = (const float*)d_in[5];
  const float* W_dt   = (const float*)d_in[6];
  const float* b_dt   = (const float*)d_in[7];
  const float* A_log  = (const float*)d_in[8];
  const float* Dw     = (const float*)d_in[9];
  const float* W_out  = (const float*)d_in[10];
  float* out = (float*)d_out;
  float* ws  = (float*)d_ws;

  // workspace layout — total 207.5 MB (< proven-safe 265.8 MB)
  float* PR  = ws;                          //  1,048,576 f32 ( 4 MB)
  float* Hws = PR + 1048576L;               //  8,388,608 f32 (32 MB)
  float* Sws = Hws + 8388608L;              //    524,288 f32 ( 2 MB)
  unsigned short* DTb  = (unsigned short*)(Sws + 524288L);  // 16.8M bf16 (32 MB)
  unsigned short* XCP  = DTb + 16777216L;                   // 32 MB
  unsigned short* Ybf  = XCP;                               // overlay (disjoint liveness)
  unsigned short* XCbf = XCP + 16777216L;                   // 32 MB
  unsigned short* RESb = XCbf + 16777216L;                  // 32 MB
  unsigned short* XB   = RESb + 16777216L;                  // 16 MB (x shadow / XN)
  unsigned short* WinT  = XB + 8388608L;                    // 16 MB [p][2048][512]
  unsigned short* WoutT = WinT + 8388608L;                  //  8 MB [p][512][1024]
  unsigned short* WxT   = WoutT + 4194304L;                 //  1 MB [p][64][1024]
  unsigned short* WdtT  = WxT + 524288L;                    // 0.5 MB [p][1024][32]

  transpose_w_kernel<<<dim3(2 * DI / 32, DM / 32, NE * NL), 256, 0, stream>>>(
      W_in, WinT, DM, 2 * DI);
  transpose_w_kernel<<<dim3(DM / 32, DI / 32, NE * NL), 256, 0, stream>>>(
      W_out, WoutT, DI, DM);
  transpose_w_kernel<<<dim3(2, DI / 32, NE * NL), 256, 0, stream>>>(
      W_x, WxT, DI, 64);
  transpose_w_kernel<<<dim3(DI / 32, 1, NE * NL), 256, 0, stream>>>(
      W_dt, WdtT, DTR, DI);
  f2bf_kernel<<<8192, 256, 0, stream>>>(x, XB);   // 8.4M elems / 4 per thread

  for (int l = 0; l < NL; ++l) {
    // 1) xr = xin @ W_in  (M=2048 N=2048 K=512): split -> XCP bf16 | RESb bf16
    gemm_bf16<3, 128, 128><<<dim3(2 * DI / 128, L_SZ / 128, B_SZ), 256, 0, stream>>>(
        XB, (long)L_SZ * DM, DM, DM, WinT, (long)(2 * DI) * DM,
        nullptr, eidp, l, nullptr, XCP, RESb, 0, (long)L_SZ * DI);

    // 2) conv + silu -> XCbf bf16  (t-blocked, weights amortized)
    conv_silu_kernel<<<B_SZ * (L_SZ / TPER) * 128 / 256, 256, 0, stream>>>(
        XCP, conv_w, conv_b, eidp, l, XCbf);

    // 3) proj = xc @ W_x -> PR fp32  (M=2048 N=64 K=1024, TM=TN=64)
    gemm_bf16<0, 64, 64><<<dim3(1, L_SZ / 64, B_SZ), 256, 0, stream>>>(
        XCbf, (long)L_SZ * DI, DI, DI, WxT, (long)64 * DI,
        nullptr, eidp, l, PR, nullptr, nullptr, 64, (long)L_SZ * 64);

    // 4) dt = softplus(PR[:,:32] @ W_dt + b_dt) -> DTb bf16
    gemm_dt<<<dim3(DI / 128, L_SZ / 128, B_SZ), 256, 0, stream>>>(
        PR, WdtT, b_dt, eidp, l, DTb);

    // 5) chunked scan -> Ybf bf16 (overlays XCP, dead after conv)
    scan_p1<<<dim3(DI / 256, NCH, B_SZ), 256, 0, stream>>>(
        DTb, XCbf, PR, A_log, eidp, l, Hws, Sws);
    scan_combine<<<(B_SZ * DI * DS) / 256, 256, 0, stream>>>(
        Hws, Sws, A_log, eidp, l);
    scan_p2<<<dim3(DI / 256, NCH, B_SZ), 256, 0, stream>>>(
        DTb, XCbf, RESb, PR, A_log, Dw, Hws, eidp, l, Ybf);

    // 6) y @ W_out  (M=2048 N=512 K=1024)
    if (l == NL - 1) {
      gemm_bf16<2, 128, 128><<<dim3(DM / 128, L_SZ / 128, B_SZ), 256, 0, stream>>>(
          Ybf, (long)L_SZ * DI, DI, DI, WoutT, (long)DM * DI,
          x, eidp, l, out, nullptr, nullptr, DM, (long)L_SZ * DM);
    } else {
      gemm_bf16<4, 128, 128><<<dim3(DM / 128, L_SZ / 128, B_SZ), 256, 0, stream>>>(
          Ybf, (long)L_SZ * DI, DI, DI, WoutT, (long)DM * DI,
          nullptr, eidp, l, nullptr, XB, nullptr, DM, (long)L_SZ * DM);
    }
  }
}